// Round 13
// baseline (388.540 us; speedup 1.0000x reference)
//
#include <hip/hip_runtime.h>
#include <math.h>

#define PI_F 3.14159265358979323846f

// broadcast lane l's value of v to all lanes (v_readlane -> SGPR)
__device__ __forceinline__ float lane_bcast(float v, int l) {
  return __int_as_float(__builtin_amdgcn_readlane(__float_as_int(v), l));
}

// ---------------- wave reduce ----------------
__device__ __forceinline__ float wave_reduce_sum(float v) {
  v += __shfl_xor(v, 32, 64);
  v += __shfl_xor(v, 16, 64);
  v += __shfl_xor(v, 8, 64);
  v += __shfl_xor(v, 4, 64);
  v += __shfl_xor(v, 2, 64);
  v += __shfl_xor(v, 1, 64);
  return v;
}

// ---------------- LayerNorm: one 64-lane wave per token (C=192) ----------------
__global__ __launch_bounds__(64) void ln_kernel(const float* __restrict__ x,
    const float* __restrict__ w, const float* __restrict__ b, float* __restrict__ o) {
  int row = blockIdx.x;
  int lane = threadIdx.x;
  const float* xr = x + row * 192;
  float v0 = xr[lane], v1 = xr[lane + 64], v2 = xr[lane + 128];
  float s  = wave_reduce_sum(v0 + v1 + v2);
  float s2 = wave_reduce_sum(v0 * v0 + v1 * v1 + v2 * v2);
  float mu  = s * (1.f / 192.f);
  float var = s2 * (1.f / 192.f) - mu * mu;
  float rs  = rsqrtf(var + 1e-5f);
  float* orow = o + row * 192;
  orow[lane]       = (v0 - mu) * rs * w[lane]       + b[lane];
  orow[lane + 64]  = (v1 - mu) * rs * w[lane + 64]  + b[lane + 64];
  orow[lane + 128] = (v2 - mu) * rs * w[lane + 128] + b[lane + 128];
}

// ---------------- pipelined tiled GEMM 64x64: C = A @ W^T (+res) ----------------
__global__ __launch_bounds__(256) void gemm_tn(const float* __restrict__ A,
    const float* __restrict__ W, const float* __restrict__ res, float* __restrict__ C,
    int M, int N, int K) {
  __shared__ float As[2][32][68];   // [buf][k][m]
  __shared__ float Ws[2][32][68];   // [buf][k][n]
  int tid = threadIdx.x;
  int m0 = blockIdx.y * 64, n0 = blockIdx.x * 64;
  int tr = tid >> 4, tc = tid & 15;
  int sm  = tid >> 3;
  int skq = tid & 7;
  float4 aP[2], wP[2];
#pragma unroll
  for (int j = 0; j < 2; ++j) {
    int m = sm + j * 32;
    aP[j] = *(const float4*)(A + (size_t)(m0 + m) * K + skq * 4);
    int n = n0 + m;
    if (n < N) wP[j] = *(const float4*)(W + (size_t)n * K + skq * 4);
    else       wP[j] = make_float4(0.f, 0.f, 0.f, 0.f);
  }
#pragma unroll
  for (int j = 0; j < 2; ++j) {
    int m = sm + j * 32;
    As[0][skq * 4 + 0][m] = aP[j].x;
    As[0][skq * 4 + 1][m] = aP[j].y;
    As[0][skq * 4 + 2][m] = aP[j].z;
    As[0][skq * 4 + 3][m] = aP[j].w;
    Ws[0][skq * 4 + 0][m] = wP[j].x;
    Ws[0][skq * 4 + 1][m] = wP[j].y;
    Ws[0][skq * 4 + 2][m] = wP[j].z;
    Ws[0][skq * 4 + 3][m] = wP[j].w;
  }
  __syncthreads();
  float acc[4][4] = {{0.f}};
  int nk = K >> 5;
  for (int it = 0; it < nk; ++it) {
    int cur = it & 1, nxt = cur ^ 1;
    if (it + 1 < nk) {
      int kk = (it + 1) << 5;
#pragma unroll
      for (int j = 0; j < 2; ++j) {
        int m = sm + j * 32;
        aP[j] = *(const float4*)(A + (size_t)(m0 + m) * K + kk + skq * 4);
        int n = n0 + m;
        if (n < N) wP[j] = *(const float4*)(W + (size_t)n * K + kk + skq * 4);
        else       wP[j] = make_float4(0.f, 0.f, 0.f, 0.f);
      }
    }
#pragma unroll
    for (int k = 0; k < 32; ++k) {
      float4 a4 = *(const float4*)&As[cur][k][tr * 4];
      float4 w4 = *(const float4*)&Ws[cur][k][tc * 4];
      float a[4] = {a4.x, a4.y, a4.z, a4.w};
      float bb[4] = {w4.x, w4.y, w4.z, w4.w};
#pragma unroll
      for (int i = 0; i < 4; ++i)
#pragma unroll
        for (int j = 0; j < 4; ++j)
          acc[i][j] = fmaf(a[i], bb[j], acc[i][j]);
    }
    if (it + 1 < nk) {
#pragma unroll
      for (int j = 0; j < 2; ++j) {
        int m = sm + j * 32;
        As[nxt][skq * 4 + 0][m] = aP[j].x;
        As[nxt][skq * 4 + 1][m] = aP[j].y;
        As[nxt][skq * 4 + 2][m] = aP[j].z;
        As[nxt][skq * 4 + 3][m] = aP[j].w;
        Ws[nxt][skq * 4 + 0][m] = wP[j].x;
        Ws[nxt][skq * 4 + 1][m] = wP[j].y;
        Ws[nxt][skq * 4 + 2][m] = wP[j].z;
        Ws[nxt][skq * 4 + 3][m] = wP[j].w;
      }
      __syncthreads();
    }
  }
#pragma unroll
  for (int i = 0; i < 4; ++i) {
    int m = m0 + tr * 4 + i;
#pragma unroll
    for (int j = 0; j < 4; ++j) {
      int n = n0 + tc * 4 + j;
      if (n < N) {
        float v = acc[i][j];
        if (res) v += res[m * N + n];
        C[m * N + n] = v;
      }
    }
  }
}

// ---------------- pipelined GEMM BM=32 x BN=64 for skinny-N ----------------
__global__ __launch_bounds__(256) void gemm_tn32(const float* __restrict__ A,
    const float* __restrict__ W, const float* __restrict__ res, float* __restrict__ C,
    int M, int N, int K) {
  __shared__ float As[2][32][36];   // [buf][k][m(32)]
  __shared__ float Ws[2][32][68];   // [buf][k][n(64)]
  int tid = threadIdx.x;
  int m0 = blockIdx.y * 32, n0 = blockIdx.x * 64;
  int tr = tid >> 4, tc = tid & 15;
  int sm  = tid >> 3;
  int skq = tid & 7;
  float4 aP, wP[2];
  aP = *(const float4*)(A + (size_t)(m0 + sm) * K + skq * 4);
#pragma unroll
  for (int j = 0; j < 2; ++j) {
    int n = n0 + sm + j * 32;
    if (n < N) wP[j] = *(const float4*)(W + (size_t)n * K + skq * 4);
    else       wP[j] = make_float4(0.f, 0.f, 0.f, 0.f);
  }
  As[0][skq * 4 + 0][sm] = aP.x;
  As[0][skq * 4 + 1][sm] = aP.y;
  As[0][skq * 4 + 2][sm] = aP.z;
  As[0][skq * 4 + 3][sm] = aP.w;
#pragma unroll
  for (int j = 0; j < 2; ++j) {
    int n = sm + j * 32;
    Ws[0][skq * 4 + 0][n] = wP[j].x;
    Ws[0][skq * 4 + 1][n] = wP[j].y;
    Ws[0][skq * 4 + 2][n] = wP[j].z;
    Ws[0][skq * 4 + 3][n] = wP[j].w;
  }
  __syncthreads();
  float acc[2][4] = {{0.f}};
  int nk = K >> 5;
  for (int it = 0; it < nk; ++it) {
    int cur = it & 1, nxt = cur ^ 1;
    if (it + 1 < nk) {
      int kk = (it + 1) << 5;
      aP = *(const float4*)(A + (size_t)(m0 + sm) * K + kk + skq * 4);
#pragma unroll
      for (int j = 0; j < 2; ++j) {
        int n = n0 + sm + j * 32;
        if (n < N) wP[j] = *(const float4*)(W + (size_t)n * K + kk + skq * 4);
        else       wP[j] = make_float4(0.f, 0.f, 0.f, 0.f);
      }
    }
#pragma unroll
    for (int k = 0; k < 32; ++k) {
      float2 a2 = *(const float2*)&As[cur][k][tr * 2];
      float4 w4 = *(const float4*)&Ws[cur][k][tc * 4];
      float a[2] = {a2.x, a2.y};
      float bb[4] = {w4.x, w4.y, w4.z, w4.w};
#pragma unroll
      for (int i = 0; i < 2; ++i)
#pragma unroll
        for (int j = 0; j < 4; ++j)
          acc[i][j] = fmaf(a[i], bb[j], acc[i][j]);
    }
    if (it + 1 < nk) {
      As[nxt][skq * 4 + 0][sm] = aP.x;
      As[nxt][skq * 4 + 1][sm] = aP.y;
      As[nxt][skq * 4 + 2][sm] = aP.z;
      As[nxt][skq * 4 + 3][sm] = aP.w;
#pragma unroll
      for (int j = 0; j < 2; ++j) {
        int n = sm + j * 32;
        Ws[nxt][skq * 4 + 0][n] = wP[j].x;
        Ws[nxt][skq * 4 + 1][n] = wP[j].y;
        Ws[nxt][skq * 4 + 2][n] = wP[j].z;
        Ws[nxt][skq * 4 + 3][n] = wP[j].w;
      }
      __syncthreads();
    }
  }
#pragma unroll
  for (int i = 0; i < 2; ++i) {
    int m = m0 + tr * 2 + i;
#pragma unroll
    for (int j = 0; j < 4; ++j) {
      int n = n0 + tc * 4 + j;
      if (n < N) {
        float v = acc[i][j];
        if (res) v += res[m * N + n];
        C[m * N + n] = v;
      }
    }
  }
}

// ---------------- gemm_tn32 with TRANSPOSED A: AT[(bb*K + k)*1024 + t] ----
__global__ __launch_bounds__(256) void gemm_at32(const float* __restrict__ AT,
    const float* __restrict__ W, const float* __restrict__ res, float* __restrict__ C,
    int M, int N, int K) {
  __shared__ float As[2][32][36];   // [buf][k][m(32)]
  __shared__ float Ws[2][32][68];   // [buf][k][n(64)]
  int tid = threadIdx.x;
  int m0 = blockIdx.y * 32, n0 = blockIdx.x * 64;
  int bb = m0 >> 10;
  int t0 = m0 & 1023;
  const float* Ab = AT + ((size_t)bb * K) * 1024 + t0;
  int tr = tid >> 4, tc = tid & 15;
  int sm  = tid >> 3;
  int skq = tid & 7;
  float4 aP, wP[2];
  aP = *(const float4*)(Ab + (size_t)sm * 1024 + skq * 4);
#pragma unroll
  for (int j = 0; j < 2; ++j) {
    int n = n0 + sm + j * 32;
    if (n < N) wP[j] = *(const float4*)(W + (size_t)n * K + skq * 4);
    else       wP[j] = make_float4(0.f, 0.f, 0.f, 0.f);
  }
  *(float4*)&As[0][sm][skq * 4] = aP;
#pragma unroll
  for (int j = 0; j < 2; ++j) {
    int n = sm + j * 32;
    Ws[0][skq * 4 + 0][n] = wP[j].x;
    Ws[0][skq * 4 + 1][n] = wP[j].y;
    Ws[0][skq * 4 + 2][n] = wP[j].z;
    Ws[0][skq * 4 + 3][n] = wP[j].w;
  }
  __syncthreads();
  float acc[2][4] = {{0.f}};
  int nk = K >> 5;
  for (int it = 0; it < nk; ++it) {
    int cur = it & 1, nxt = cur ^ 1;
    if (it + 1 < nk) {
      int kk = (it + 1) << 5;
      aP = *(const float4*)(Ab + (size_t)(kk + sm) * 1024 + skq * 4);
#pragma unroll
      for (int j = 0; j < 2; ++j) {
        int n = n0 + sm + j * 32;
        if (n < N) wP[j] = *(const float4*)(W + (size_t)n * K + kk + skq * 4);
        else       wP[j] = make_float4(0.f, 0.f, 0.f, 0.f);
      }
    }
#pragma unroll
    for (int k = 0; k < 32; ++k) {
      float2 a2 = *(const float2*)&As[cur][k][tr * 2];
      float4 w4 = *(const float4*)&Ws[cur][k][tc * 4];
      float a[2] = {a2.x, a2.y};
      float bb4[4] = {w4.x, w4.y, w4.z, w4.w};
#pragma unroll
      for (int i = 0; i < 2; ++i)
#pragma unroll
        for (int j = 0; j < 4; ++j)
          acc[i][j] = fmaf(a[i], bb4[j], acc[i][j]);
    }
    if (it + 1 < nk) {
      *(float4*)&As[nxt][sm][skq * 4] = aP;
#pragma unroll
      for (int j = 0; j < 2; ++j) {
        int n = sm + j * 32;
        Ws[nxt][skq * 4 + 0][n] = wP[j].x;
        Ws[nxt][skq * 4 + 1][n] = wP[j].y;
        Ws[nxt][skq * 4 + 2][n] = wP[j].z;
        Ws[nxt][skq * 4 + 3][n] = wP[j].w;
      }
      __syncthreads();
    }
  }
#pragma unroll
  for (int i = 0; i < 2; ++i) {
    int m = m0 + tr * 2 + i;
#pragma unroll
    for (int j = 0; j < 4; ++j) {
      int n = n0 + tc * 4 + j;
      if (n < N) {
        float v = acc[i][j];
        if (res) v += res[m * N + n];
        C[m * N + n] = v;
      }
    }
  }
}

// ---------------- causal depthwise conv1d(k=4) + SiLU ----------------
__global__ __launch_bounds__(256) void conv_silu(const float* __restrict__ xz,
    const float* __restrict__ cw, const float* __restrict__ cb, float* __restrict__ xc) {
  int e = blockIdx.x * 256 + threadIdx.x;
  if (e >= 4 * 1024 * 384) return;
  int d = e % 384;
  int t = (e / 384) % 1024;
  int b = e / (384 * 1024);
  const float* base = xz + (size_t)(b * 1024) * 768 + d;
  float acc = cb[d];
#pragma unroll
  for (int j = 0; j < 4; ++j) {
    int tt = t - 3 + j;
    if (tt >= 0) acc += base[(size_t)tt * 768] * cw[d * 4 + j];
  }
  float sg = 1.f / (1.f + __expf(-acc));
  xc[e] = acc * sg;
}

// ---------------- delta + transpose: dltT, duT = dlt*xc, zT (z half of xz) ----
__global__ __launch_bounds__(256) void delta_trans(const float* __restrict__ dbc,
    const float* __restrict__ dtw, const float* __restrict__ dtb,
    const float* __restrict__ xc, const float* __restrict__ xz,
    float* __restrict__ dltT, float* __restrict__ duT, float* __restrict__ zT) {
  __shared__ float dts[64][13];
  __shared__ float xt[64][65];
  __shared__ float zt[64][65];
  int blk = blockIdx.x;           // 4 * 16 * 6 = 384
  int b  = blk / 96;
  int rem = blk % 96;
  int tt = rem / 6, dd = rem % 6;
  int t0 = tt * 64, d0 = dd * 64;
  int tid = threadIdx.x;
  for (int i = tid; i < 64 * 12; i += 256) {
    int tl = i / 12, r = i % 12;
    dts[tl][r] = dbc[((size_t)b * 1024 + t0 + tl) * 140 + r];
  }
  {
    int col = tid & 63, rg = tid >> 6;
#pragma unroll
    for (int j = 0; j < 16; ++j) {
      int row = j * 4 + rg;
      xt[row][col] = xc[((size_t)b * 1024 + t0 + row) * 384 + d0 + col];
      zt[row][col] = xz[((size_t)b * 1024 + t0 + row) * 768 + 384 + d0 + col];
    }
  }
  __syncthreads();
  int tl = tid & 63, grp = tid >> 6;
#pragma unroll
  for (int j = 0; j < 16; ++j) {
    int dl = grp * 16 + j;
    int d = d0 + dl;
    float s = dtb[d];
#pragma unroll
    for (int r = 0; r < 12; ++r) s += dts[tl][r] * dtw[d * 12 + r];
    float dlt = (s > 20.f) ? s : log1pf(__expf(s));
    size_t ob = ((size_t)b * 384 + d) * 1024 + t0 + tl;
    dltT[ob] = dlt;
    duT[ob]  = dlt * xt[tl][dl];
    zT[ob]   = zt[tl][dl];
  }
}

// ---------------- FUSED selective scan: p1+p2+p3+gate, one block per (b,d) ----
// Bumped-pointer B/C loads (const imm offsets <4088B); gate inputs all
// coalesced: xc = duT/dltT (transposed, L1-hot), z from zT.
__global__ __launch_bounds__(512) void scan_fused(const float* __restrict__ dltT,
    const float* __restrict__ duT, const float* __restrict__ dbc,
    const float* __restrict__ A_log, const float* __restrict__ zT,
    const float* __restrict__ Dvec, float* __restrict__ yT) {
  __shared__ float tile[8][16][65];
  __shared__ float psP[8][64];
  __shared__ float psS[8][64];
  int bd = blockIdx.x;
  int b = bd / 384, d = bd % 384;
  int tid = threadIdx.x;
  int c = tid >> 6;        // wave index = chunk
  int lane = tid & 63;
  float A = -__expf(A_log[d * 64 + lane]) * 1.44269504f;
  int t0 = c * 128;
  const float* dT = dltT + ((size_t)b * 384 + d) * 1024 + t0;
  const float* uT = duT  + ((size_t)b * 384 + d) * 1024 + t0;
  const float* Bp = dbc + ((size_t)b * 1024 + t0) * 140 + 12 + lane;
  // ---- phase 1: chunk summary ----
  float Sv = 0.f, sdvtot = 0.f;
#pragma unroll
  for (int half = 0; half < 2; ++half) {
    float dv64 = dT[half * 64 + lane];
    float du64 = uT[half * 64 + lane];
    sdvtot += dv64;
    for (int tb = 0; tb < 64; tb += 16) {
      int ts = half * 64 + tb;
      const float* Bq = Bp + (size_t)ts * 140;
      float Bv[16];
#pragma unroll
      for (int g = 0; g < 2; ++g) {
#pragma unroll
        for (int i = 0; i < 8; ++i) Bv[g * 8 + i] = Bq[i * 140];
        Bq += 1120;
      }
#pragma unroll
      for (int i = 0; i < 16; ++i) {
        float sdv = lane_bcast(dv64, tb + i);
        float sdu = lane_bcast(du64, tb + i);
        float a = exp2f(sdv * A);
        Sv = fmaf(Sv, a, sdu * Bv[i]);
      }
    }
  }
  float Pv = exp2f(A * wave_reduce_sum(sdvtot));   // product of decays = exp of sum
  psP[c][lane] = Pv;
  psS[c][lane] = Sv;
  __syncthreads();
  // ---- combine: h_init for this wave's chunk ----
  float h = 0.f;
  for (int k = 0; k < c; ++k)
    h = fmaf(psP[k][lane], h, psS[k][lane]);
  // ---- phase 2: replay + gated coalesced write ----
  float ddv = Dvec[d];
  float* yp = yT + ((size_t)b * 384 + d) * 1024 + t0;
  const float* zq = zT + ((size_t)b * 384 + d) * 1024 + t0;
  int tq = lane & 15;
  int q  = lane >> 4;
#pragma unroll
  for (int half = 0; half < 2; ++half) {
    float dv64 = dT[half * 64 + lane];
    float du64 = uT[half * 64 + lane];
    for (int tb = 0; tb < 64; tb += 16) {
      int ts = half * 64 + tb;
      const float* Bq = Bp + (size_t)ts * 140;
      const float* Cq = Bq + 64;
      float Bv[16], Cv[16];
#pragma unroll
      for (int g = 0; g < 2; ++g) {
#pragma unroll
        for (int i = 0; i < 8; ++i) {
          Bv[g * 8 + i] = Bq[i * 140];
          Cv[g * 8 + i] = Cq[i * 140];
        }
        Bq += 1120; Cq += 1120;
      }
      float xcv = 0.f, zv = 0.f;
      if (lane < 16) {
        float dvl = dT[ts + lane];   // coalesced 64B, L1-hot
        float dul = uT[ts + lane];
        xcv = dul / dvl;             // xc = (delta*xc)/delta
        zv  = zq[ts + lane];
      }
#pragma unroll
      for (int i = 0; i < 16; ++i) {
        float sdv = lane_bcast(dv64, tb + i);
        float sdu = lane_bcast(du64, tb + i);
        float a = exp2f(sdv * A);
        h = fmaf(h, a, sdu * Bv[i]);
        tile[c][i][lane] = h * Cv[i];
      }
      const float* trow = &tile[c][tq][q * 16];
      float s = 0.f;
#pragma unroll
      for (int i = 0; i < 16; ++i) s += trow[i];
      s += __shfl_xor(s, 16, 64);
      s += __shfl_xor(s, 32, 64);
      if (lane < 16) {
        float sg = zv / (1.f + __expf(-zv));
        yp[ts + lane] = (s + xcv * ddv) * sg;
      }
    }
  }
}

// ---------------- 1024-pt radix-2 FFT in LDS with twiddle table ----------------
__device__ __forceinline__ void fft1024t(float* __restrict__ re,
    float* __restrict__ im, const float* __restrict__ twc,
    const float* __restrict__ tws, int tid) {
  for (int i = tid; i < 1024; i += 256) {
    int r = (int)(__brev((unsigned)i) >> 22);
    if (i < r) {
      float tr = re[i]; re[i] = re[r]; re[r] = tr;
      float ti = im[i]; im[i] = im[r]; im[r] = ti;
    }
  }
  __syncthreads();
  for (int s = 0; s < 10; ++s) {
    int half = 1 << s;
    int shift = 9 - s;
#pragma unroll
    for (int uu = 0; uu < 2; ++uu) {
      int u = tid + uu * 256;
      int j = u & (half - 1);
      int i0 = ((u >> s) << (s + 1)) + j;
      int i1 = i0 + half;
      int idx = j << shift;
      float cw = twc[idx];
      float sw = tws[idx];
      float br = re[i1], bi = im[i1];
      float tr = br * cw - bi * sw;
      float ti = br * sw + bi * cw;
      float ar = re[i0], ai = im[i0];
      re[i1] = ar - tr; im[i1] = ai - ti;
      re[i0] = ar + tr; im[i0] = ai + ti;
    }
    __syncthreads();
  }
}

// forward fft2: one block per (Bi,d,c). Inline 4-pt DFT over c on load.
__global__ __launch_bounds__(256) void fft_fwd(const float* __restrict__ xin,
    float* __restrict__ Xre, float* __restrict__ Xim) {
  __shared__ float re[1024];
  __shared__ float im[1024];
  __shared__ float twc[512];
  __shared__ float tws[512];
  int blk = blockIdx.x;
  int c = blk & 3;
  int rest = blk >> 2;
  int d = rest % 48, Bi = rest / 48;
  int tid = threadIdx.x;
  for (int k = tid; k < 512; k += 256) {
    float sv, cv;
    __sincosf(-PI_F * (float)k * (1.f / 512.f), &sv, &cv);
    twc[k] = cv; tws[k] = sv;
  }
  for (int n = tid; n < 1024; n += 256) {
    const float* p = xin + (size_t)(Bi * 1024 + n) * 192 + d;
    float v0 = p[0], v1 = p[48], v2 = p[96], v3 = p[144];
    float rr, ii;
    if (c == 0)      { rr = v0 + v1 + v2 + v3; ii = 0.f; }
    else if (c == 1) { rr = v0 - v2;           ii = -(v1 - v3); }
    else if (c == 2) { rr = v0 - v1 + v2 - v3; ii = 0.f; }
    else             { rr = v0 - v2;           ii = (v1 - v3); }
    re[n] = rr; im[n] = ii;
  }
  __syncthreads();
  fft1024t(re, im, twc, tws, tid);
  for (int k = tid; k < 1024; k += 256) {
    size_t o = ((size_t)(Bi * 1024 + k) * 4 + c) * 48 + d;
    Xre[o] = re[k] * (1.f / 64.f);
    Xim[o] = im[k] * (1.f / 64.f);
  }
}

// ---------------- EinFFT frequency mix, layer 1 ----------------
__global__ __launch_bounds__(256) void mix_l1(const float* __restrict__ Xre,
    const float* __restrict__ Xim, const float* __restrict__ cw1,
    const float* __restrict__ cb1, float* __restrict__ r1, float* __restrict__ i1) {
  int e = blockIdx.x * 256 + threadIdx.x;   // [0, 786432)
  int j = e % 48;
  int row = e / 48;
  int b = row & 3;
  const float* wr = cw1 + b * 2304;
  const float* wi = cw1 + 9216 + b * 2304;
  const float* xr = Xre + (size_t)row * 48;
  const float* xi = Xim + (size_t)row * 48;
  float ar = cb1[b * 48 + j];
  float ai = cb1[192 + b * 48 + j];
#pragma unroll 12
  for (int dd = 0; dd < 48; ++dd) {
    float xrv = xr[dd], xiv = xi[dd];
    float wrv = wr[dd * 48 + j], wiv = wi[dd * 48 + j];
    ar = fmaf(xrv, wrv, ar);
    ar = fmaf(-xiv, wiv, ar);
    ai = fmaf(xrv, wiv, ai);
    ai = fmaf(xiv, wrv, ai);
  }
  r1[e] = fmaxf(ar, 0.f);
  i1[e] = fmaxf(ai, 0.f);
}

// layer 2 + softshrink, writes Z in-place over X
__global__ __launch_bounds__(256) void mix_l2(const float* __restrict__ r1,
    const float* __restrict__ i1, const float* __restrict__ cw2,
    const float* __restrict__ cb2, float* __restrict__ Xre, float* __restrict__ Xim) {
  int e = blockIdx.x * 256 + threadIdx.x;
  int j = e % 48;
  int row = e / 48;
  int b = row & 3;
  const float* wr = cw2 + b * 2304;
  const float* wi = cw2 + 9216 + b * 2304;
  const float* rr = r1 + (size_t)row * 48;
  const float* ri = i1 + (size_t)row * 48;
  float ar = cb2[b * 48 + j];
  float ai = cb2[192 + b * 48 + j];
#pragma unroll 12
  for (int dd = 0; dd < 48; ++dd) {
    float rv = rr[dd], iv = ri[dd];
    float wrv = wr[dd * 48 + j], wiv = wi[dd * 48 + j];
    ar = fmaf(rv, wrv, ar);
    ar = fmaf(-iv, wiv, ar);
    ai = fmaf(rv, wiv, ai);
    ai = fmaf(iv, wrv, ai);
  }
  float zr = (ar > 0.01f) ? ar - 0.01f : ((ar < -0.01f) ? ar + 0.01f : 0.f);
  float zi = (ai > 0.01f) ? ai - 0.01f : ((ai < -0.01f) ? ai + 0.01f : 0.f);
  Xre[e] = zr;
  Xim[e] = zi;
}

// inverse fft2: one block per (Bi,d,c). Inline inverse 4-pt DFT on load,
// IFFT, add residual, write real part.
__global__ __launch_bounds__(256) void fft_inv(const float* __restrict__ Zre,
    const float* __restrict__ Zim, const float* __restrict__ x1, float* __restrict__ out) {
  __shared__ float re[1024];
  __shared__ float im[1024];
  __shared__ float twc[512];
  __shared__ float tws[512];
  int blk = blockIdx.x;
  int c = blk & 3;
  int rest = blk >> 2;
  int d = rest % 48, Bi = rest / 48;
  int tid = threadIdx.x;
  for (int k = tid; k < 512; k += 256) {
    float sv, cv;
    __sincosf(PI_F * (float)k * (1.f / 512.f), &sv, &cv);
    twc[k] = cv; tws[k] = sv;
  }
  for (int k = tid; k < 1024; k += 256) {
    size_t o = ((size_t)(Bi * 1024 + k) * 4) * 48 + d;
    float r0 = Zre[o], r1v = Zre[o + 48], r2 = Zre[o + 96], r3 = Zre[o + 144];
    float i0 = Zim[o], i1v = Zim[o + 48], i2 = Zim[o + 96], i3 = Zim[o + 144];
    float rr, ii;
    if (c == 0)      { rr = r0 + r1v + r2 + r3;  ii = i0 + i1v + i2 + i3; }
    else if (c == 1) { rr = r0 - i1v - r2 + i3;  ii = i0 + r1v - i2 - r3; }
    else if (c == 2) { rr = r0 - r1v + r2 - r3;  ii = i0 - i1v + i2 - i3; }
    else             { rr = r0 + i1v - r2 - i3;  ii = i0 - r1v - i2 + r3; }
    re[k] = rr; im[k] = ii;
  }
  __syncthreads();
  fft1024t(re, im, twc, tws, tid);
  for (int n = tid; n < 1024; n += 256) {
    size_t o = (size_t)(Bi * 1024 + n) * 192 + c * 48 + d;
    out[o] = x1[o] + re[n] * (1.f / 64.f);
  }
}

extern "C" void kernel_launch(void* const* d_in, const int* in_sizes, int n_in,
                              void* d_out, int out_size, void* d_ws, size_t ws_size,
                              hipStream_t stream) {
  const float* x         = (const float*)d_in[0];
  const float* ln1_w     = (const float*)d_in[1];
  const float* ln1_b     = (const float*)d_in[2];
  const float* in_proj_w = (const float*)d_in[3];
  const float* conv_w    = (const float*)d_in[4];
  const float* conv_b    = (const float*)d_in[5];
  const float* x_proj_w  = (const float*)d_in[6];
  const float* dt_proj_w = (const float*)d_in[7];
  const float* dt_proj_b = (const float*)d_in[8];
  const float* A_log     = (const float*)d_in[9];
  const float* Dvec      = (const float*)d_in[10];
  const float* out_proj_w= (const float*)d_in[11];
  const float* ln2_w     = (const float*)d_in[12];
  const float* ln2_b     = (const float*)d_in[13];
  const float* cw1       = (const float*)d_in[14];
  const float* cw2       = (const float*)d_in[15];
  const float* cb1       = (const float*)d_in[16];
  const float* cb2       = (const float*)d_in[17];
  float* out = (float*)d_out;
  float* ws  = (float*)d_ws;

  // workspace layout (floats). Aliases:
  //  duT = Xre+Xim region (dead until fft_fwd), dltT in dlt's slot,
  //  zT = xln+x2 region (dead between in_proj and out_proj/ln2),
  //  r1/i1 alias dltT/yvT (dead after scan / out_proj), x1 = xln.
  float* xz   = ws;                    // 3145728
  float* xc   = xz  + 3145728;         // 1572864
  float* dbc  = xc  + 1572864;         // 573440
  float* dltT = dbc + 573440;          // 1572864
  float* yvT  = dltT + 1572864;        // 1572864 (TRANSPOSED y: [b][d][t])
  float* xln  = yvT + 1572864;         // 786432
  float* x2   = xln + 786432;          // 786432
  float* Xre  = x2  + 786432;          // 786432
  float* Xim  = Xre + 786432;          // 786432
  float* duT = Xre;                    // 1572864 (spans Xre+Xim)
  float* zTp = xln;                    // 1572864 (spans xln+x2)
  float* r1 = dltT;
  float* i1 = yvT;
  float* x1 = xln;

  ln_kernel<<<4096, 64, 0, stream>>>(x, ln1_w, ln1_b, xln);
  gemm_tn<<<dim3(12, 64), 256, 0, stream>>>(xln, in_proj_w, nullptr, xz, 4096, 768, 192);
  conv_silu<<<6144, 256, 0, stream>>>(xz, conv_w, conv_b, xc);
  gemm_tn32<<<dim3(3, 128), 256, 0, stream>>>(xc, x_proj_w, nullptr, dbc, 4096, 140, 384);
  delta_trans<<<384, 256, 0, stream>>>(dbc, dt_proj_w, dt_proj_b, xc, xz, dltT, duT, zTp);
  scan_fused<<<1536, 512, 0, stream>>>(dltT, duT, dbc, A_log, zTp, Dvec, yvT);
  gemm_at32<<<dim3(3, 128), 256, 0, stream>>>(yvT, out_proj_w, x, x1, 4096, 192, 384);
  ln_kernel<<<4096, 64, 0, stream>>>(x1, ln2_w, ln2_b, x2);
  fft_fwd<<<768, 256, 0, stream>>>(x2, Xre, Xim);
  mix_l1<<<3072, 256, 0, stream>>>(Xre, Xim, cw1, cb1, r1, i1);
  mix_l2<<<3072, 256, 0, stream>>>(r1, i1, cw2, cb2, Xre, Xim);
  fft_inv<<<768, 256, 0, stream>>>(Xre, Xim, x1, out);
}

// Round 14
// 384.851 us; speedup vs baseline: 1.0096x; 1.0096x over previous
//
#include <hip/hip_runtime.h>
#include <math.h>

#define PI_F 3.14159265358979323846f

// broadcast lane l's value of v to all lanes (v_readlane -> SGPR)
__device__ __forceinline__ float lane_bcast(float v, int l) {
  return __int_as_float(__builtin_amdgcn_readlane(__float_as_int(v), l));
}

// ---------------- wave reduce ----------------
__device__ __forceinline__ float wave_reduce_sum(float v) {
  v += __shfl_xor(v, 32, 64);
  v += __shfl_xor(v, 16, 64);
  v += __shfl_xor(v, 8, 64);
  v += __shfl_xor(v, 4, 64);
  v += __shfl_xor(v, 2, 64);
  v += __shfl_xor(v, 1, 64);
  return v;
}

// ---------------- LayerNorm: one 64-lane wave per token (C=192) ----------------
__global__ __launch_bounds__(64) void ln_kernel(const float* __restrict__ x,
    const float* __restrict__ w, const float* __restrict__ b, float* __restrict__ o) {
  int row = blockIdx.x;
  int lane = threadIdx.x;
  const float* xr = x + row * 192;
  float v0 = xr[lane], v1 = xr[lane + 64], v2 = xr[lane + 128];
  float s  = wave_reduce_sum(v0 + v1 + v2);
  float s2 = wave_reduce_sum(v0 * v0 + v1 * v1 + v2 * v2);
  float mu  = s * (1.f / 192.f);
  float var = s2 * (1.f / 192.f) - mu * mu;
  float rs  = rsqrtf(var + 1e-5f);
  float* orow = o + row * 192;
  orow[lane]       = (v0 - mu) * rs * w[lane]       + b[lane];
  orow[lane + 64]  = (v1 - mu) * rs * w[lane + 64]  + b[lane + 64];
  orow[lane + 128] = (v2 - mu) * rs * w[lane + 128] + b[lane + 128];
}

// ---------------- pipelined tiled GEMM 64x64: C = A @ W^T (+res) ----------------
__global__ __launch_bounds__(256) void gemm_tn(const float* __restrict__ A,
    const float* __restrict__ W, const float* __restrict__ res, float* __restrict__ C,
    int M, int N, int K) {
  __shared__ float As[2][32][68];   // [buf][k][m]
  __shared__ float Ws[2][32][68];   // [buf][k][n]
  int tid = threadIdx.x;
  int m0 = blockIdx.y * 64, n0 = blockIdx.x * 64;
  int tr = tid >> 4, tc = tid & 15;
  int sm  = tid >> 3;
  int skq = tid & 7;
  float4 aP[2], wP[2];
#pragma unroll
  for (int j = 0; j < 2; ++j) {
    int m = sm + j * 32;
    aP[j] = *(const float4*)(A + (size_t)(m0 + m) * K + skq * 4);
    int n = n0 + m;
    if (n < N) wP[j] = *(const float4*)(W + (size_t)n * K + skq * 4);
    else       wP[j] = make_float4(0.f, 0.f, 0.f, 0.f);
  }
#pragma unroll
  for (int j = 0; j < 2; ++j) {
    int m = sm + j * 32;
    As[0][skq * 4 + 0][m] = aP[j].x;
    As[0][skq * 4 + 1][m] = aP[j].y;
    As[0][skq * 4 + 2][m] = aP[j].z;
    As[0][skq * 4 + 3][m] = aP[j].w;
    Ws[0][skq * 4 + 0][m] = wP[j].x;
    Ws[0][skq * 4 + 1][m] = wP[j].y;
    Ws[0][skq * 4 + 2][m] = wP[j].z;
    Ws[0][skq * 4 + 3][m] = wP[j].w;
  }
  __syncthreads();
  float acc[4][4] = {{0.f}};
  int nk = K >> 5;
  for (int it = 0; it < nk; ++it) {
    int cur = it & 1, nxt = cur ^ 1;
    if (it + 1 < nk) {
      int kk = (it + 1) << 5;
#pragma unroll
      for (int j = 0; j < 2; ++j) {
        int m = sm + j * 32;
        aP[j] = *(const float4*)(A + (size_t)(m0 + m) * K + kk + skq * 4);
        int n = n0 + m;
        if (n < N) wP[j] = *(const float4*)(W + (size_t)n * K + kk + skq * 4);
        else       wP[j] = make_float4(0.f, 0.f, 0.f, 0.f);
      }
    }
#pragma unroll
    for (int k = 0; k < 32; ++k) {
      float4 a4 = *(const float4*)&As[cur][k][tr * 4];
      float4 w4 = *(const float4*)&Ws[cur][k][tc * 4];
      float a[4] = {a4.x, a4.y, a4.z, a4.w};
      float bb[4] = {w4.x, w4.y, w4.z, w4.w};
#pragma unroll
      for (int i = 0; i < 4; ++i)
#pragma unroll
        for (int j = 0; j < 4; ++j)
          acc[i][j] = fmaf(a[i], bb[j], acc[i][j]);
    }
    if (it + 1 < nk) {
#pragma unroll
      for (int j = 0; j < 2; ++j) {
        int m = sm + j * 32;
        As[nxt][skq * 4 + 0][m] = aP[j].x;
        As[nxt][skq * 4 + 1][m] = aP[j].y;
        As[nxt][skq * 4 + 2][m] = aP[j].z;
        As[nxt][skq * 4 + 3][m] = aP[j].w;
        Ws[nxt][skq * 4 + 0][m] = wP[j].x;
        Ws[nxt][skq * 4 + 1][m] = wP[j].y;
        Ws[nxt][skq * 4 + 2][m] = wP[j].z;
        Ws[nxt][skq * 4 + 3][m] = wP[j].w;
      }
      __syncthreads();
    }
  }
#pragma unroll
  for (int i = 0; i < 4; ++i) {
    int m = m0 + tr * 4 + i;
#pragma unroll
    for (int j = 0; j < 4; ++j) {
      int n = n0 + tc * 4 + j;
      if (n < N) {
        float v = acc[i][j];
        if (res) v += res[m * N + n];
        C[m * N + n] = v;
      }
    }
  }
}

// ---------------- pipelined GEMM BM=32 x BN=64 for skinny-N ----------------
__global__ __launch_bounds__(256) void gemm_tn32(const float* __restrict__ A,
    const float* __restrict__ W, const float* __restrict__ res, float* __restrict__ C,
    int M, int N, int K) {
  __shared__ float As[2][32][36];   // [buf][k][m(32)]
  __shared__ float Ws[2][32][68];   // [buf][k][n(64)]
  int tid = threadIdx.x;
  int m0 = blockIdx.y * 32, n0 = blockIdx.x * 64;
  int tr = tid >> 4, tc = tid & 15;
  int sm  = tid >> 3;
  int skq = tid & 7;
  float4 aP, wP[2];
  aP = *(const float4*)(A + (size_t)(m0 + sm) * K + skq * 4);
#pragma unroll
  for (int j = 0; j < 2; ++j) {
    int n = n0 + sm + j * 32;
    if (n < N) wP[j] = *(const float4*)(W + (size_t)n * K + skq * 4);
    else       wP[j] = make_float4(0.f, 0.f, 0.f, 0.f);
  }
  As[0][skq * 4 + 0][sm] = aP.x;
  As[0][skq * 4 + 1][sm] = aP.y;
  As[0][skq * 4 + 2][sm] = aP.z;
  As[0][skq * 4 + 3][sm] = aP.w;
#pragma unroll
  for (int j = 0; j < 2; ++j) {
    int n = sm + j * 32;
    Ws[0][skq * 4 + 0][n] = wP[j].x;
    Ws[0][skq * 4 + 1][n] = wP[j].y;
    Ws[0][skq * 4 + 2][n] = wP[j].z;
    Ws[0][skq * 4 + 3][n] = wP[j].w;
  }
  __syncthreads();
  float acc[2][4] = {{0.f}};
  int nk = K >> 5;
  for (int it = 0; it < nk; ++it) {
    int cur = it & 1, nxt = cur ^ 1;
    if (it + 1 < nk) {
      int kk = (it + 1) << 5;
      aP = *(const float4*)(A + (size_t)(m0 + sm) * K + kk + skq * 4);
#pragma unroll
      for (int j = 0; j < 2; ++j) {
        int n = n0 + sm + j * 32;
        if (n < N) wP[j] = *(const float4*)(W + (size_t)n * K + kk + skq * 4);
        else       wP[j] = make_float4(0.f, 0.f, 0.f, 0.f);
      }
    }
#pragma unroll
    for (int k = 0; k < 32; ++k) {
      float2 a2 = *(const float2*)&As[cur][k][tr * 2];
      float4 w4 = *(const float4*)&Ws[cur][k][tc * 4];
      float a[2] = {a2.x, a2.y};
      float bb[4] = {w4.x, w4.y, w4.z, w4.w};
#pragma unroll
      for (int i = 0; i < 2; ++i)
#pragma unroll
        for (int j = 0; j < 4; ++j)
          acc[i][j] = fmaf(a[i], bb[j], acc[i][j]);
    }
    if (it + 1 < nk) {
      As[nxt][skq * 4 + 0][sm] = aP.x;
      As[nxt][skq * 4 + 1][sm] = aP.y;
      As[nxt][skq * 4 + 2][sm] = aP.z;
      As[nxt][skq * 4 + 3][sm] = aP.w;
#pragma unroll
      for (int j = 0; j < 2; ++j) {
        int n = sm + j * 32;
        Ws[nxt][skq * 4 + 0][n] = wP[j].x;
        Ws[nxt][skq * 4 + 1][n] = wP[j].y;
        Ws[nxt][skq * 4 + 2][n] = wP[j].z;
        Ws[nxt][skq * 4 + 3][n] = wP[j].w;
      }
      __syncthreads();
    }
  }
#pragma unroll
  for (int i = 0; i < 2; ++i) {
    int m = m0 + tr * 2 + i;
#pragma unroll
    for (int j = 0; j < 4; ++j) {
      int n = n0 + tc * 4 + j;
      if (n < N) {
        float v = acc[i][j];
        if (res) v += res[m * N + n];
        C[m * N + n] = v;
      }
    }
  }
}

// ---------------- gemm_tn32 with TRANSPOSED A: AT[(bb*K + k)*1024 + t] ----
__global__ __launch_bounds__(256) void gemm_at32(const float* __restrict__ AT,
    const float* __restrict__ W, const float* __restrict__ res, float* __restrict__ C,
    int M, int N, int K) {
  __shared__ float As[2][32][36];   // [buf][k][m(32)]
  __shared__ float Ws[2][32][68];   // [buf][k][n(64)]
  int tid = threadIdx.x;
  int m0 = blockIdx.y * 32, n0 = blockIdx.x * 64;
  int bb = m0 >> 10;
  int t0 = m0 & 1023;
  const float* Ab = AT + ((size_t)bb * K) * 1024 + t0;
  int tr = tid >> 4, tc = tid & 15;
  int sm  = tid >> 3;
  int skq = tid & 7;
  float4 aP, wP[2];
  aP = *(const float4*)(Ab + (size_t)sm * 1024 + skq * 4);
#pragma unroll
  for (int j = 0; j < 2; ++j) {
    int n = n0 + sm + j * 32;
    if (n < N) wP[j] = *(const float4*)(W + (size_t)n * K + skq * 4);
    else       wP[j] = make_float4(0.f, 0.f, 0.f, 0.f);
  }
  *(float4*)&As[0][sm][skq * 4] = aP;
#pragma unroll
  for (int j = 0; j < 2; ++j) {
    int n = sm + j * 32;
    Ws[0][skq * 4 + 0][n] = wP[j].x;
    Ws[0][skq * 4 + 1][n] = wP[j].y;
    Ws[0][skq * 4 + 2][n] = wP[j].z;
    Ws[0][skq * 4 + 3][n] = wP[j].w;
  }
  __syncthreads();
  float acc[2][4] = {{0.f}};
  int nk = K >> 5;
  for (int it = 0; it < nk; ++it) {
    int cur = it & 1, nxt = cur ^ 1;
    if (it + 1 < nk) {
      int kk = (it + 1) << 5;
      aP = *(const float4*)(Ab + (size_t)(kk + sm) * 1024 + skq * 4);
#pragma unroll
      for (int j = 0; j < 2; ++j) {
        int n = n0 + sm + j * 32;
        if (n < N) wP[j] = *(const float4*)(W + (size_t)n * K + kk + skq * 4);
        else       wP[j] = make_float4(0.f, 0.f, 0.f, 0.f);
      }
    }
#pragma unroll
    for (int k = 0; k < 32; ++k) {
      float2 a2 = *(const float2*)&As[cur][k][tr * 2];
      float4 w4 = *(const float4*)&Ws[cur][k][tc * 4];
      float a[2] = {a2.x, a2.y};
      float bb4[4] = {w4.x, w4.y, w4.z, w4.w};
#pragma unroll
      for (int i = 0; i < 2; ++i)
#pragma unroll
        for (int j = 0; j < 4; ++j)
          acc[i][j] = fmaf(a[i], bb4[j], acc[i][j]);
    }
    if (it + 1 < nk) {
      *(float4*)&As[nxt][sm][skq * 4] = aP;
#pragma unroll
      for (int j = 0; j < 2; ++j) {
        int n = sm + j * 32;
        Ws[nxt][skq * 4 + 0][n] = wP[j].x;
        Ws[nxt][skq * 4 + 1][n] = wP[j].y;
        Ws[nxt][skq * 4 + 2][n] = wP[j].z;
        Ws[nxt][skq * 4 + 3][n] = wP[j].w;
      }
      __syncthreads();
    }
  }
#pragma unroll
  for (int i = 0; i < 2; ++i) {
    int m = m0 + tr * 2 + i;
#pragma unroll
    for (int j = 0; j < 4; ++j) {
      int n = n0 + tc * 4 + j;
      if (n < N) {
        float v = acc[i][j];
        if (res) v += res[m * N + n];
        C[m * N + n] = v;
      }
    }
  }
}

// ---------------- causal depthwise conv1d(k=4) + SiLU ----------------
__global__ __launch_bounds__(256) void conv_silu(const float* __restrict__ xz,
    const float* __restrict__ cw, const float* __restrict__ cb, float* __restrict__ xc) {
  int e = blockIdx.x * 256 + threadIdx.x;
  if (e >= 4 * 1024 * 384) return;
  int d = e % 384;
  int t = (e / 384) % 1024;
  int b = e / (384 * 1024);
  const float* base = xz + (size_t)(b * 1024) * 768 + d;
  float acc = cb[d];
#pragma unroll
  for (int j = 0; j < 4; ++j) {
    int tt = t - 3 + j;
    if (tt >= 0) acc += base[(size_t)tt * 768] * cw[d * 4 + j];
  }
  float sg = 1.f / (1.f + __expf(-acc));
  xc[e] = acc * sg;
}

// ---------------- delta + transpose: dltT[b,d,t], duT[b,d,t] = dlt*xc ------
__global__ __launch_bounds__(256) void delta_trans(const float* __restrict__ dbc,
    const float* __restrict__ dtw, const float* __restrict__ dtb,
    const float* __restrict__ xc, float* __restrict__ dltT, float* __restrict__ duT) {
  __shared__ float dts[64][13];
  __shared__ float xt[64][65];
  int blk = blockIdx.x;           // 4 * 16 * 6 = 384
  int b  = blk / 96;
  int rem = blk % 96;
  int tt = rem / 6, dd = rem % 6;
  int t0 = tt * 64, d0 = dd * 64;
  int tid = threadIdx.x;
  for (int i = tid; i < 64 * 12; i += 256) {
    int tl = i / 12, r = i % 12;
    dts[tl][r] = dbc[((size_t)b * 1024 + t0 + tl) * 140 + r];
  }
  {
    int col = tid & 63, rg = tid >> 6;
#pragma unroll
    for (int j = 0; j < 16; ++j) {
      int row = j * 4 + rg;
      xt[row][col] = xc[((size_t)b * 1024 + t0 + row) * 384 + d0 + col];
    }
  }
  __syncthreads();
  int tl = tid & 63, grp = tid >> 6;
#pragma unroll
  for (int j = 0; j < 16; ++j) {
    int dl = grp * 16 + j;
    int d = d0 + dl;
    float s = dtb[d];
#pragma unroll
    for (int r = 0; r < 12; ++r) s += dts[tl][r] * dtw[d * 12 + r];
    float dlt = (s > 20.f) ? s : log1pf(__expf(s));
    size_t ob = ((size_t)b * 384 + d) * 1024 + t0 + tl;
    dltT[ob] = dlt;
    duT[ob]  = dlt * xt[tl][dl];
  }
}

// ---------------- FUSED selective scan (R11-proven, 97.3us) ----------------
__global__ __launch_bounds__(512) void scan_fused(const float* __restrict__ dltT,
    const float* __restrict__ duT, const float* __restrict__ dbc,
    const float* __restrict__ A_log, const float* __restrict__ xc,
    const float* __restrict__ xz, const float* __restrict__ Dvec,
    float* __restrict__ yT) {
  __shared__ float tile[8][16][65];
  __shared__ float psP[8][64];
  __shared__ float psS[8][64];
  int bd = blockIdx.x;
  int b = bd / 384, d = bd % 384;
  int tid = threadIdx.x;
  int c = tid >> 6;        // wave index = chunk
  int lane = tid & 63;
  float A = -__expf(A_log[d * 64 + lane]) * 1.44269504f;
  int t0 = c * 128;
  const float* dT = dltT + ((size_t)b * 384 + d) * 1024 + t0;
  const float* uT = duT  + ((size_t)b * 384 + d) * 1024 + t0;
  const float* Bp = dbc + ((size_t)b * 1024 + t0) * 140 + 12 + lane;
  const float* Cp = Bp + 64;
  // ---- phase 1: chunk summary ----
  float Pv = 1.f, Sv = 0.f;
#pragma unroll
  for (int half = 0; half < 2; ++half) {
    float dv64 = dT[half * 64 + lane];
    float du64 = uT[half * 64 + lane];
    for (int tb = 0; tb < 64; tb += 16) {
      float Bv[16];
#pragma unroll
      for (int i = 0; i < 16; ++i)
        Bv[i] = Bp[(size_t)(half * 64 + tb + i) * 140];
#pragma unroll
      for (int i = 0; i < 16; ++i) {
        float sdv = lane_bcast(dv64, tb + i);
        float sdu = lane_bcast(du64, tb + i);
        float a = exp2f(sdv * A);
        Pv *= a;
        Sv = fmaf(Sv, a, sdu * Bv[i]);
      }
    }
  }
  psP[c][lane] = Pv;
  psS[c][lane] = Sv;
  __syncthreads();
  // ---- combine: h_init for this wave's chunk ----
  float h = 0.f;
  for (int k = 0; k < c; ++k)
    h = fmaf(psP[k][lane], h, psS[k][lane]);
  // ---- phase 2: replay + gated coalesced write ----
  float ddv = Dvec[d];
  float* yp = yT + ((size_t)b * 384 + d) * 1024 + t0;
  const float* xcp = xc + ((size_t)b * 1024 + t0) * 384 + d;
  const float* xzp = xz + ((size_t)b * 1024 + t0) * 768 + 384 + d;
  int tq = lane & 15;
  int q  = lane >> 4;
#pragma unroll
  for (int half = 0; half < 2; ++half) {
    float dv64 = dT[half * 64 + lane];
    float du64 = uT[half * 64 + lane];
    for (int tb = 0; tb < 64; tb += 16) {
      int ts = half * 64 + tb;
      float Bv[16], Cv[16];
#pragma unroll
      for (int i = 0; i < 16; ++i) {
        size_t ro = (size_t)(ts + i) * 140;
        Bv[i] = Bp[ro];
        Cv[i] = Cp[ro];
      }
      float xcv = 0.f, zv = 0.f;
      if (lane < 16) {
        xcv = xcp[(size_t)(ts + lane) * 384];
        zv  = xzp[(size_t)(ts + lane) * 768];
      }
#pragma unroll
      for (int i = 0; i < 16; ++i) {
        float sdv = lane_bcast(dv64, tb + i);
        float sdu = lane_bcast(du64, tb + i);
        float a = exp2f(sdv * A);
        h = fmaf(h, a, sdu * Bv[i]);
        tile[c][i][lane] = h * Cv[i];
      }
      const float* trow = &tile[c][tq][q * 16];
      float s = 0.f;
#pragma unroll
      for (int i = 0; i < 16; ++i) s += trow[i];
      s += __shfl_xor(s, 16, 64);
      s += __shfl_xor(s, 32, 64);
      if (lane < 16) {
        float sg = zv / (1.f + __expf(-zv));
        yp[ts + lane] = (s + xcv * ddv) * sg;
      }
    }
  }
}

// ---------------- radix-4 1024-pt FFT in LDS ----------------
// digit-reverse base-4 of a 10-bit index: bit-reverse then swap bit pairs
__device__ __forceinline__ int rev4_10(int i) {
  unsigned r = __brev((unsigned)i) >> 22;
  return (int)(((r & 0x155u) << 1) | ((r >> 1) & 0x155u));
}

// tw tables (768 entries): twc[k]=cos(sgn*2pi*k/1024), tws[k]=sin(sgn*2pi*k/1024)
// sgn = -1 forward, +1 inverse (must match table fill).
__device__ __forceinline__ void fft1024r4(float* __restrict__ re,
    float* __restrict__ im, const float* __restrict__ twc,
    const float* __restrict__ tws, int tid, float sgn) {
  // digit-reverse permutation
  for (int i = tid; i < 1024; i += 256) {
    int r = rev4_10(i);
    if (i < r) {
      float t = re[i]; re[i] = re[r]; re[r] = t;
      t = im[i]; im[i] = im[r]; im[r] = t;
    }
  }
  __syncthreads();
  // stage 0: L=1, twiddles = 1, 4 consecutive points -> float4 in/out
  {
    float4 ar = *(float4*)&re[tid * 4];
    float4 ai = *(float4*)&im[tid * 4];
    float apc_r = ar.x + ar.z, amc_r = ar.x - ar.z;
    float apc_i = ai.x + ai.z, amc_i = ai.x - ai.z;
    float bpd_r = ar.y + ar.w, bmd_r = ar.y - ar.w;
    float bpd_i = ai.y + ai.w, bmd_i = ai.y - ai.w;
    float4 yr, yi;
    yr.x = apc_r + bpd_r;        yi.x = apc_i + bpd_i;
    yr.z = apc_r - bpd_r;        yi.z = apc_i - bpd_i;
    yr.y = amc_r - sgn * bmd_i;  yi.y = amc_i + sgn * bmd_r;
    yr.w = amc_r + sgn * bmd_i;  yi.w = amc_i - sgn * bmd_r;
    *(float4*)&re[tid * 4] = yr;
    *(float4*)&im[tid * 4] = yi;
  }
  __syncthreads();
  // stages 1..4: L = 4^s
#pragma unroll
  for (int s = 1; s < 5; ++s) {
    int L = 1 << (2 * s);
    int tstep = 256 >> (2 * s);
    int j = tid & (L - 1);
    int base = ((tid >> (2 * s)) << (2 * s + 2)) + j;
    int i0 = base, i1 = base + L, i2 = base + 2 * L, i3 = base + 3 * L;
    int x1i = j * tstep;
    float w1c = twc[x1i],     w1s = tws[x1i];
    float w2c = twc[2 * x1i], w2s = tws[2 * x1i];
    float w3c = twc[3 * x1i], w3s = tws[3 * x1i];
    float ar_ = re[i0], ai_ = im[i0];
    float br_ = re[i1], bi_ = im[i1];
    float cr_ = re[i2], ci_ = im[i2];
    float dr_ = re[i3], di_ = im[i3];
    float tbr = br_ * w1c - bi_ * w1s, tbi = br_ * w1s + bi_ * w1c;
    float tcr = cr_ * w2c - ci_ * w2s, tci = cr_ * w2s + ci_ * w2c;
    float tdr = dr_ * w3c - di_ * w3s, tdi = dr_ * w3s + di_ * w3c;
    float apc_r = ar_ + tcr, amc_r = ar_ - tcr;
    float apc_i = ai_ + tci, amc_i = ai_ - tci;
    float bpd_r = tbr + tdr, bmd_r = tbr - tdr;
    float bpd_i = tbi + tdi, bmd_i = tbi - tdi;
    re[i0] = apc_r + bpd_r;       im[i0] = apc_i + bpd_i;
    re[i2] = apc_r - bpd_r;       im[i2] = apc_i - bpd_i;
    re[i1] = amc_r - sgn * bmd_i; im[i1] = amc_i + sgn * bmd_r;
    re[i3] = amc_r + sgn * bmd_i; im[i3] = amc_i - sgn * bmd_r;
    __syncthreads();
  }
}

// forward fft2: one block per (Bi,d,c). Inline 4-pt DFT over c on load.
__global__ __launch_bounds__(256) void fft_fwd(const float* __restrict__ xin,
    float* __restrict__ Xre, float* __restrict__ Xim) {
  __shared__ float re[1024];
  __shared__ float im[1024];
  __shared__ float twc[768];
  __shared__ float tws[768];
  int blk = blockIdx.x;
  int c = blk & 3;
  int rest = blk >> 2;
  int d = rest % 48, Bi = rest / 48;
  int tid = threadIdx.x;
  for (int k = tid; k < 768; k += 256) {
    float sv, cv;
    __sincosf(-PI_F * (float)k * (1.f / 512.f), &sv, &cv);
    twc[k] = cv; tws[k] = sv;
  }
  for (int n = tid; n < 1024; n += 256) {
    const float* p = xin + (size_t)(Bi * 1024 + n) * 192 + d;
    float v0 = p[0], v1 = p[48], v2 = p[96], v3 = p[144];
    float rr, ii;
    if (c == 0)      { rr = v0 + v1 + v2 + v3; ii = 0.f; }
    else if (c == 1) { rr = v0 - v2;           ii = -(v1 - v3); }
    else if (c == 2) { rr = v0 - v1 + v2 - v3; ii = 0.f; }
    else             { rr = v0 - v2;           ii = (v1 - v3); }
    re[n] = rr; im[n] = ii;
  }
  __syncthreads();
  fft1024r4(re, im, twc, tws, tid, -1.0f);
  for (int k = tid; k < 1024; k += 256) {
    size_t o = ((size_t)(Bi * 1024 + k) * 4 + c) * 48 + d;
    Xre[o] = re[k] * (1.f / 64.f);
    Xim[o] = im[k] * (1.f / 64.f);
  }
}

// ---------------- EinFFT frequency mix, layer 1 ----------------
__global__ __launch_bounds__(256) void mix_l1(const float* __restrict__ Xre,
    const float* __restrict__ Xim, const float* __restrict__ cw1,
    const float* __restrict__ cb1, float* __restrict__ r1, float* __restrict__ i1) {
  int e = blockIdx.x * 256 + threadIdx.x;   // [0, 786432)
  int j = e % 48;
  int row = e / 48;
  int b = row & 3;
  const float* wr = cw1 + b * 2304;
  const float* wi = cw1 + 9216 + b * 2304;
  const float* xr = Xre + (size_t)row * 48;
  const float* xi = Xim + (size_t)row * 48;
  float ar = cb1[b * 48 + j];
  float ai = cb1[192 + b * 48 + j];
#pragma unroll 12
  for (int dd = 0; dd < 48; ++dd) {
    float xrv = xr[dd], xiv = xi[dd];
    float wrv = wr[dd * 48 + j], wiv = wi[dd * 48 + j];
    ar = fmaf(xrv, wrv, ar);
    ar = fmaf(-xiv, wiv, ar);
    ai = fmaf(xrv, wiv, ai);
    ai = fmaf(xiv, wrv, ai);
  }
  r1[e] = fmaxf(ar, 0.f);
  i1[e] = fmaxf(ai, 0.f);
}

// layer 2 + softshrink, writes Z in-place over X
__global__ __launch_bounds__(256) void mix_l2(const float* __restrict__ r1,
    const float* __restrict__ i1, const float* __restrict__ cw2,
    const float* __restrict__ cb2, float* __restrict__ Xre, float* __restrict__ Xim) {
  int e = blockIdx.x * 256 + threadIdx.x;
  int j = e % 48;
  int row = e / 48;
  int b = row & 3;
  const float* wr = cw2 + b * 2304;
  const float* wi = cw2 + 9216 + b * 2304;
  const float* rr = r1 + (size_t)row * 48;
  const float* ri = i1 + (size_t)row * 48;
  float ar = cb2[b * 48 + j];
  float ai = cb2[192 + b * 48 + j];
#pragma unroll 12
  for (int dd = 0; dd < 48; ++dd) {
    float rv = rr[dd], iv = ri[dd];
    float wrv = wr[dd * 48 + j], wiv = wi[dd * 48 + j];
    ar = fmaf(rv, wrv, ar);
    ar = fmaf(-iv, wiv, ar);
    ai = fmaf(rv, wiv, ai);
    ai = fmaf(iv, wrv, ai);
  }
  float zr = (ar > 0.01f) ? ar - 0.01f : ((ar < -0.01f) ? ar + 0.01f : 0.f);
  float zi = (ai > 0.01f) ? ai - 0.01f : ((ai < -0.01f) ? ai + 0.01f : 0.f);
  Xre[e] = zr;
  Xim[e] = zi;
}

// inverse fft2: one block per (Bi,d,c). Inline inverse 4-pt DFT on load,
// IFFT, add residual, write real part.
__global__ __launch_bounds__(256) void fft_inv(const float* __restrict__ Zre,
    const float* __restrict__ Zim, const float* __restrict__ x1, float* __restrict__ out) {
  __shared__ float re[1024];
  __shared__ float im[1024];
  __shared__ float twc[768];
  __shared__ float tws[768];
  int blk = blockIdx.x;
  int c = blk & 3;
  int rest = blk >> 2;
  int d = rest % 48, Bi = rest / 48;
  int tid = threadIdx.x;
  for (int k = tid; k < 768; k += 256) {
    float sv, cv;
    __sincosf(PI_F * (float)k * (1.f / 512.f), &sv, &cv);
    twc[k] = cv; tws[k] = sv;
  }
  for (int k = tid; k < 1024; k += 256) {
    size_t o = ((size_t)(Bi * 1024 + k) * 4) * 48 + d;
    float r0 = Zre[o], r1v = Zre[o + 48], r2 = Zre[o + 96], r3 = Zre[o + 144];
    float i0 = Zim[o], i1v = Zim[o + 48], i2 = Zim[o + 96], i3 = Zim[o + 144];
    float rr, ii;
    if (c == 0)      { rr = r0 + r1v + r2 + r3;  ii = i0 + i1v + i2 + i3; }
    else if (c == 1) { rr = r0 - i1v - r2 + i3;  ii = i0 + r1v - i2 - r3; }
    else if (c == 2) { rr = r0 - r1v + r2 - r3;  ii = i0 - i1v + i2 - i3; }
    else             { rr = r0 + i1v - r2 - i3;  ii = i0 - r1v - i2 + r3; }
    re[k] = rr; im[k] = ii;
  }
  __syncthreads();
  fft1024r4(re, im, twc, tws, tid, 1.0f);
  for (int n = tid; n < 1024; n += 256) {
    size_t o = (size_t)(Bi * 1024 + n) * 192 + c * 48 + d;
    out[o] = x1[o] + re[n] * (1.f / 64.f);
  }
}

extern "C" void kernel_launch(void* const* d_in, const int* in_sizes, int n_in,
                              void* d_out, int out_size, void* d_ws, size_t ws_size,
                              hipStream_t stream) {
  const float* x         = (const float*)d_in[0];
  const float* ln1_w     = (const float*)d_in[1];
  const float* ln1_b     = (const float*)d_in[2];
  const float* in_proj_w = (const float*)d_in[3];
  const float* conv_w    = (const float*)d_in[4];
  const float* conv_b    = (const float*)d_in[5];
  const float* x_proj_w  = (const float*)d_in[6];
  const float* dt_proj_w = (const float*)d_in[7];
  const float* dt_proj_b = (const float*)d_in[8];
  const float* A_log     = (const float*)d_in[9];
  const float* Dvec      = (const float*)d_in[10];
  const float* out_proj_w= (const float*)d_in[11];
  const float* ln2_w     = (const float*)d_in[12];
  const float* ln2_b     = (const float*)d_in[13];
  const float* cw1       = (const float*)d_in[14];
  const float* cw2       = (const float*)d_in[15];
  const float* cb1       = (const float*)d_in[16];
  const float* cb2       = (const float*)d_in[17];
  float* out = (float*)d_out;
  float* ws  = (float*)d_ws;

  // workspace layout (floats). Aliases:
  //  duT = Xre+Xim region (dead until fft_fwd), dltT in dlt's slot,
  //  r1/i1 alias dltT/yvT (dead after scan / out_proj), x1 = xln.
  float* xz   = ws;                    // 3145728
  float* xc   = xz  + 3145728;         // 1572864
  float* dbc  = xc  + 1572864;         // 573440
  float* dltT = dbc + 573440;          // 1572864
  float* yvT  = dltT + 1572864;        // 1572864 (TRANSPOSED y: [b][d][t])
  float* xln  = yvT + 1572864;         // 786432
  float* x2   = xln + 786432;          // 786432
  float* Xre  = x2  + 786432;          // 786432
  float* Xim  = Xre + 786432;          // 786432
  float* duT = Xre;                    // 1572864 (spans Xre+Xim)
  float* r1 = dltT;
  float* i1 = yvT;
  float* x1 = xln;

  ln_kernel<<<4096, 64, 0, stream>>>(x, ln1_w, ln1_b, xln);
  gemm_tn<<<dim3(12, 64), 256, 0, stream>>>(xln, in_proj_w, nullptr, xz, 4096, 768, 192);
  conv_silu<<<6144, 256, 0, stream>>>(xz, conv_w, conv_b, xc);
  gemm_tn32<<<dim3(3, 128), 256, 0, stream>>>(xc, x_proj_w, nullptr, dbc, 4096, 140, 384);
  delta_trans<<<384, 256, 0, stream>>>(dbc, dt_proj_w, dt_proj_b, xc, dltT, duT);
  scan_fused<<<1536, 512, 0, stream>>>(dltT, duT, dbc, A_log, xc, xz, Dvec, yvT);
  gemm_at32<<<dim3(3, 128), 256, 0, stream>>>(yvT, out_proj_w, x, x1, 4096, 192, 384);
  ln_kernel<<<4096, 64, 0, stream>>>(x1, ln2_w, ln2_b, x2);
  fft_fwd<<<768, 256, 0, stream>>>(x2, Xre, Xim);
  mix_l1<<<3072, 256, 0, stream>>>(Xre, Xim, cw1, cb1, r1, i1);
  mix_l2<<<3072, 256, 0, stream>>>(r1, i1, cw2, cb2, Xre, Xim);
  fft_inv<<<768, 256, 0, stream>>>(Xre, Xim, x1, out);
}

// Round 15
// 380.892 us; speedup vs baseline: 1.0201x; 1.0104x over previous
//
#include <hip/hip_runtime.h>
#include <math.h>

#define PI_F 3.14159265358979323846f

// broadcast lane l's value of v to all lanes (v_readlane -> SGPR)
__device__ __forceinline__ float lane_bcast(float v, int l) {
  return __int_as_float(__builtin_amdgcn_readlane(__float_as_int(v), l));
}

// ---------------- wave reduce ----------------
__device__ __forceinline__ float wave_reduce_sum(float v) {
  v += __shfl_xor(v, 32, 64);
  v += __shfl_xor(v, 16, 64);
  v += __shfl_xor(v, 8, 64);
  v += __shfl_xor(v, 4, 64);
  v += __shfl_xor(v, 2, 64);
  v += __shfl_xor(v, 1, 64);
  return v;
}

// ---------------- LayerNorm: 4 rows per 256-thread block (wave per row) ------
__global__ __launch_bounds__(256) void ln_kernel(const float* __restrict__ x,
    const float* __restrict__ w, const float* __restrict__ b, float* __restrict__ o) {
  int row = blockIdx.x * 4 + (threadIdx.x >> 6);
  int lane = threadIdx.x & 63;
  const float* xr = x + (size_t)row * 192;
  float v0 = xr[lane], v1 = xr[lane + 64], v2 = xr[lane + 128];
  float s  = wave_reduce_sum(v0 + v1 + v2);
  float s2 = wave_reduce_sum(v0 * v0 + v1 * v1 + v2 * v2);
  float mu  = s * (1.f / 192.f);
  float var = s2 * (1.f / 192.f) - mu * mu;
  float rs  = rsqrtf(var + 1e-5f);
  float* orow = o + (size_t)row * 192;
  orow[lane]       = (v0 - mu) * rs * w[lane]       + b[lane];
  orow[lane + 64]  = (v1 - mu) * rs * w[lane + 64]  + b[lane + 64];
  orow[lane + 128] = (v2 - mu) * rs * w[lane + 128] + b[lane + 128];
}

// ---------------- pipelined tiled GEMM 64x64: C = A @ W^T (+res) ----------------
__global__ __launch_bounds__(256) void gemm_tn(const float* __restrict__ A,
    const float* __restrict__ W, const float* __restrict__ res, float* __restrict__ C,
    int M, int N, int K) {
  __shared__ float As[2][32][68];   // [buf][k][m]
  __shared__ float Ws[2][32][68];   // [buf][k][n]
  int tid = threadIdx.x;
  int m0 = blockIdx.y * 64, n0 = blockIdx.x * 64;
  int tr = tid >> 4, tc = tid & 15;
  int sm  = tid >> 3;
  int skq = tid & 7;
  float4 aP[2], wP[2];
#pragma unroll
  for (int j = 0; j < 2; ++j) {
    int m = sm + j * 32;
    aP[j] = *(const float4*)(A + (size_t)(m0 + m) * K + skq * 4);
    int n = n0 + m;
    if (n < N) wP[j] = *(const float4*)(W + (size_t)n * K + skq * 4);
    else       wP[j] = make_float4(0.f, 0.f, 0.f, 0.f);
  }
#pragma unroll
  for (int j = 0; j < 2; ++j) {
    int m = sm + j * 32;
    As[0][skq * 4 + 0][m] = aP[j].x;
    As[0][skq * 4 + 1][m] = aP[j].y;
    As[0][skq * 4 + 2][m] = aP[j].z;
    As[0][skq * 4 + 3][m] = aP[j].w;
    Ws[0][skq * 4 + 0][m] = wP[j].x;
    Ws[0][skq * 4 + 1][m] = wP[j].y;
    Ws[0][skq * 4 + 2][m] = wP[j].z;
    Ws[0][skq * 4 + 3][m] = wP[j].w;
  }
  __syncthreads();
  float acc[4][4] = {{0.f}};
  int nk = K >> 5;
  for (int it = 0; it < nk; ++it) {
    int cur = it & 1, nxt = cur ^ 1;
    if (it + 1 < nk) {
      int kk = (it + 1) << 5;
#pragma unroll
      for (int j = 0; j < 2; ++j) {
        int m = sm + j * 32;
        aP[j] = *(const float4*)(A + (size_t)(m0 + m) * K + kk + skq * 4);
        int n = n0 + m;
        if (n < N) wP[j] = *(const float4*)(W + (size_t)n * K + kk + skq * 4);
        else       wP[j] = make_float4(0.f, 0.f, 0.f, 0.f);
      }
    }
#pragma unroll
    for (int k = 0; k < 32; ++k) {
      float4 a4 = *(const float4*)&As[cur][k][tr * 4];
      float4 w4 = *(const float4*)&Ws[cur][k][tc * 4];
      float a[4] = {a4.x, a4.y, a4.z, a4.w};
      float bb[4] = {w4.x, w4.y, w4.z, w4.w};
#pragma unroll
      for (int i = 0; i < 4; ++i)
#pragma unroll
        for (int j = 0; j < 4; ++j)
          acc[i][j] = fmaf(a[i], bb[j], acc[i][j]);
    }
    if (it + 1 < nk) {
#pragma unroll
      for (int j = 0; j < 2; ++j) {
        int m = sm + j * 32;
        As[nxt][skq * 4 + 0][m] = aP[j].x;
        As[nxt][skq * 4 + 1][m] = aP[j].y;
        As[nxt][skq * 4 + 2][m] = aP[j].z;
        As[nxt][skq * 4 + 3][m] = aP[j].w;
        Ws[nxt][skq * 4 + 0][m] = wP[j].x;
        Ws[nxt][skq * 4 + 1][m] = wP[j].y;
        Ws[nxt][skq * 4 + 2][m] = wP[j].z;
        Ws[nxt][skq * 4 + 3][m] = wP[j].w;
      }
      __syncthreads();
    }
  }
#pragma unroll
  for (int i = 0; i < 4; ++i) {
    int m = m0 + tr * 4 + i;
#pragma unroll
    for (int j = 0; j < 4; ++j) {
      int n = n0 + tc * 4 + j;
      if (n < N) {
        float v = acc[i][j];
        if (res) v += res[m * N + n];
        C[m * N + n] = v;
      }
    }
  }
}

// ---------------- pipelined GEMM BM=32 x BN=64 for skinny-N ----------------
__global__ __launch_bounds__(256) void gemm_tn32(const float* __restrict__ A,
    const float* __restrict__ W, const float* __restrict__ res, float* __restrict__ C,
    int M, int N, int K) {
  __shared__ float As[2][32][36];   // [buf][k][m(32)]
  __shared__ float Ws[2][32][68];   // [buf][k][n(64)]
  int tid = threadIdx.x;
  int m0 = blockIdx.y * 32, n0 = blockIdx.x * 64;
  int tr = tid >> 4, tc = tid & 15;
  int sm  = tid >> 3;
  int skq = tid & 7;
  float4 aP, wP[2];
  aP = *(const float4*)(A + (size_t)(m0 + sm) * K + skq * 4);
#pragma unroll
  for (int j = 0; j < 2; ++j) {
    int n = n0 + sm + j * 32;
    if (n < N) wP[j] = *(const float4*)(W + (size_t)n * K + skq * 4);
    else       wP[j] = make_float4(0.f, 0.f, 0.f, 0.f);
  }
  As[0][skq * 4 + 0][sm] = aP.x;
  As[0][skq * 4 + 1][sm] = aP.y;
  As[0][skq * 4 + 2][sm] = aP.z;
  As[0][skq * 4 + 3][sm] = aP.w;
#pragma unroll
  for (int j = 0; j < 2; ++j) {
    int n = sm + j * 32;
    Ws[0][skq * 4 + 0][n] = wP[j].x;
    Ws[0][skq * 4 + 1][n] = wP[j].y;
    Ws[0][skq * 4 + 2][n] = wP[j].z;
    Ws[0][skq * 4 + 3][n] = wP[j].w;
  }
  __syncthreads();
  float acc[2][4] = {{0.f}};
  int nk = K >> 5;
  for (int it = 0; it < nk; ++it) {
    int cur = it & 1, nxt = cur ^ 1;
    if (it + 1 < nk) {
      int kk = (it + 1) << 5;
      aP = *(const float4*)(A + (size_t)(m0 + sm) * K + kk + skq * 4);
#pragma unroll
      for (int j = 0; j < 2; ++j) {
        int n = n0 + sm + j * 32;
        if (n < N) wP[j] = *(const float4*)(W + (size_t)n * K + kk + skq * 4);
        else       wP[j] = make_float4(0.f, 0.f, 0.f, 0.f);
      }
    }
#pragma unroll
    for (int k = 0; k < 32; ++k) {
      float2 a2 = *(const float2*)&As[cur][k][tr * 2];
      float4 w4 = *(const float4*)&Ws[cur][k][tc * 4];
      float a[2] = {a2.x, a2.y};
      float bb[4] = {w4.x, w4.y, w4.z, w4.w};
#pragma unroll
      for (int i = 0; i < 2; ++i)
#pragma unroll
        for (int j = 0; j < 4; ++j)
          acc[i][j] = fmaf(a[i], bb[j], acc[i][j]);
    }
    if (it + 1 < nk) {
      As[nxt][skq * 4 + 0][sm] = aP.x;
      As[nxt][skq * 4 + 1][sm] = aP.y;
      As[nxt][skq * 4 + 2][sm] = aP.z;
      As[nxt][skq * 4 + 3][sm] = aP.w;
#pragma unroll
      for (int j = 0; j < 2; ++j) {
        int n = sm + j * 32;
        Ws[nxt][skq * 4 + 0][n] = wP[j].x;
        Ws[nxt][skq * 4 + 1][n] = wP[j].y;
        Ws[nxt][skq * 4 + 2][n] = wP[j].z;
        Ws[nxt][skq * 4 + 3][n] = wP[j].w;
      }
      __syncthreads();
    }
  }
#pragma unroll
  for (int i = 0; i < 2; ++i) {
    int m = m0 + tr * 2 + i;
#pragma unroll
    for (int j = 0; j < 4; ++j) {
      int n = n0 + tc * 4 + j;
      if (n < N) {
        float v = acc[i][j];
        if (res) v += res[m * N + n];
        C[m * N + n] = v;
      }
    }
  }
}

// ---------------- gemm_tn32 with TRANSPOSED A: AT[(bb*K + k)*1024 + t] ----
__global__ __launch_bounds__(256) void gemm_at32(const float* __restrict__ AT,
    const float* __restrict__ W, const float* __restrict__ res, float* __restrict__ C,
    int M, int N, int K) {
  __shared__ float As[2][32][36];   // [buf][k][m(32)]
  __shared__ float Ws[2][32][68];   // [buf][k][n(64)]
  int tid = threadIdx.x;
  int m0 = blockIdx.y * 32, n0 = blockIdx.x * 64;
  int bb = m0 >> 10;
  int t0 = m0 & 1023;
  const float* Ab = AT + ((size_t)bb * K) * 1024 + t0;
  int tr = tid >> 4, tc = tid & 15;
  int sm  = tid >> 3;
  int skq = tid & 7;
  float4 aP, wP[2];
  aP = *(const float4*)(Ab + (size_t)sm * 1024 + skq * 4);
#pragma unroll
  for (int j = 0; j < 2; ++j) {
    int n = n0 + sm + j * 32;
    if (n < N) wP[j] = *(const float4*)(W + (size_t)n * K + skq * 4);
    else       wP[j] = make_float4(0.f, 0.f, 0.f, 0.f);
  }
  *(float4*)&As[0][sm][skq * 4] = aP;
#pragma unroll
  for (int j = 0; j < 2; ++j) {
    int n = sm + j * 32;
    Ws[0][skq * 4 + 0][n] = wP[j].x;
    Ws[0][skq * 4 + 1][n] = wP[j].y;
    Ws[0][skq * 4 + 2][n] = wP[j].z;
    Ws[0][skq * 4 + 3][n] = wP[j].w;
  }
  __syncthreads();
  float acc[2][4] = {{0.f}};
  int nk = K >> 5;
  for (int it = 0; it < nk; ++it) {
    int cur = it & 1, nxt = cur ^ 1;
    if (it + 1 < nk) {
      int kk = (it + 1) << 5;
      aP = *(const float4*)(Ab + (size_t)(kk + sm) * 1024 + skq * 4);
#pragma unroll
      for (int j = 0; j < 2; ++j) {
        int n = n0 + sm + j * 32;
        if (n < N) wP[j] = *(const float4*)(W + (size_t)n * K + kk + skq * 4);
        else       wP[j] = make_float4(0.f, 0.f, 0.f, 0.f);
      }
    }
#pragma unroll
    for (int k = 0; k < 32; ++k) {
      float2 a2 = *(const float2*)&As[cur][k][tr * 2];
      float4 w4 = *(const float4*)&Ws[cur][k][tc * 4];
      float a[2] = {a2.x, a2.y};
      float bb4[4] = {w4.x, w4.y, w4.z, w4.w};
#pragma unroll
      for (int i = 0; i < 2; ++i)
#pragma unroll
        for (int j = 0; j < 4; ++j)
          acc[i][j] = fmaf(a[i], bb4[j], acc[i][j]);
    }
    if (it + 1 < nk) {
      *(float4*)&As[nxt][sm][skq * 4] = aP;
#pragma unroll
      for (int j = 0; j < 2; ++j) {
        int n = sm + j * 32;
        Ws[nxt][skq * 4 + 0][n] = wP[j].x;
        Ws[nxt][skq * 4 + 1][n] = wP[j].y;
        Ws[nxt][skq * 4 + 2][n] = wP[j].z;
        Ws[nxt][skq * 4 + 3][n] = wP[j].w;
      }
      __syncthreads();
    }
  }
#pragma unroll
  for (int i = 0; i < 2; ++i) {
    int m = m0 + tr * 2 + i;
#pragma unroll
    for (int j = 0; j < 4; ++j) {
      int n = n0 + tc * 4 + j;
      if (n < N) {
        float v = acc[i][j];
        if (res) v += res[m * N + n];
        C[m * N + n] = v;
      }
    }
  }
}

// ---------------- causal depthwise conv1d(k=4) + SiLU, float4 over d --------
__global__ __launch_bounds__(256) void conv_silu(const float* __restrict__ xz,
    const float* __restrict__ cw, const float* __restrict__ cb, float* __restrict__ xc) {
  int e4 = blockIdx.x * 256 + threadIdx.x;   // [0, 393216)
  if (e4 >= 4 * 1024 * 96) return;
  int d4 = e4 % 96;
  int t  = (e4 / 96) % 1024;
  int b  = e4 / (96 * 1024);
  int d = d4 * 4;
  const float* base = xz + (size_t)(b * 1024) * 768 + d;
  float4 acc = *(const float4*)(cb + d);
  const float4* cwv = (const float4*)(cw + d * 4);   // cw[d..d+3][0..3], 16 floats
  float4 c0 = cwv[0], c1 = cwv[1], c2 = cwv[2], c3 = cwv[3];
#pragma unroll
  for (int j = 0; j < 4; ++j) {
    int tt = t - 3 + j;
    if (tt >= 0) {
      float4 v = *(const float4*)(base + (size_t)tt * 768);
      float w0 = (&c0.x)[j], w1 = (&c1.x)[j], w2 = (&c2.x)[j], w3 = (&c3.x)[j];
      acc.x = fmaf(v.x, w0, acc.x);
      acc.y = fmaf(v.y, w1, acc.y);
      acc.z = fmaf(v.z, w2, acc.z);
      acc.w = fmaf(v.w, w3, acc.w);
    }
  }
  float4 o;
  o.x = acc.x / (1.f + __expf(-acc.x));
  o.y = acc.y / (1.f + __expf(-acc.y));
  o.z = acc.z / (1.f + __expf(-acc.z));
  o.w = acc.w / (1.f + __expf(-acc.w));
  *(float4*)(xc + ((size_t)(b * 1024 + t) * 384) + d) = o;
}

// ---------------- delta + transpose: dltT[b,d,t], duT[b,d,t] = dlt*xc ------
__global__ __launch_bounds__(256) void delta_trans(const float* __restrict__ dbc,
    const float* __restrict__ dtw, const float* __restrict__ dtb,
    const float* __restrict__ xc, float* __restrict__ dltT, float* __restrict__ duT) {
  __shared__ float dts[64][13];
  __shared__ float xt[64][65];
  int blk = blockIdx.x;           // 4 * 16 * 6 = 384
  int b  = blk / 96;
  int rem = blk % 96;
  int tt = rem / 6, dd = rem % 6;
  int t0 = tt * 64, d0 = dd * 64;
  int tid = threadIdx.x;
  for (int i = tid; i < 64 * 12; i += 256) {
    int tl = i / 12, r = i % 12;
    dts[tl][r] = dbc[((size_t)b * 1024 + t0 + tl) * 140 + r];
  }
  {
    int col = tid & 63, rg = tid >> 6;
#pragma unroll
    for (int j = 0; j < 16; ++j) {
      int row = j * 4 + rg;
      xt[row][col] = xc[((size_t)b * 1024 + t0 + row) * 384 + d0 + col];
    }
  }
  __syncthreads();
  int tl = tid & 63, grp = tid >> 6;
#pragma unroll
  for (int j = 0; j < 16; ++j) {
    int dl = grp * 16 + j;
    int d = d0 + dl;
    float s = dtb[d];
#pragma unroll
    for (int r = 0; r < 12; ++r) s += dts[tl][r] * dtw[d * 12 + r];
    float dlt = (s > 20.f) ? s : log1pf(__expf(s));
    size_t ob = ((size_t)b * 384 + d) * 1024 + t0 + tl;
    dltT[ob] = dlt;
    duT[ob]  = dlt * xt[tl][dl];
  }
}

// ---------------- FUSED selective scan (R11-proven, ~96us) ----------------
__global__ __launch_bounds__(512) void scan_fused(const float* __restrict__ dltT,
    const float* __restrict__ duT, const float* __restrict__ dbc,
    const float* __restrict__ A_log, const float* __restrict__ xc,
    const float* __restrict__ xz, const float* __restrict__ Dvec,
    float* __restrict__ yT) {
  __shared__ float tile[8][16][65];
  __shared__ float psP[8][64];
  __shared__ float psS[8][64];
  int bd = blockIdx.x;
  int b = bd / 384, d = bd % 384;
  int tid = threadIdx.x;
  int c = tid >> 6;        // wave index = chunk
  int lane = tid & 63;
  float A = -__expf(A_log[d * 64 + lane]) * 1.44269504f;
  int t0 = c * 128;
  const float* dT = dltT + ((size_t)b * 384 + d) * 1024 + t0;
  const float* uT = duT  + ((size_t)b * 384 + d) * 1024 + t0;
  const float* Bp = dbc + ((size_t)b * 1024 + t0) * 140 + 12 + lane;
  const float* Cp = Bp + 64;
  // ---- phase 1: chunk summary ----
  float Pv = 1.f, Sv = 0.f;
#pragma unroll
  for (int half = 0; half < 2; ++half) {
    float dv64 = dT[half * 64 + lane];
    float du64 = uT[half * 64 + lane];
    for (int tb = 0; tb < 64; tb += 16) {
      float Bv[16];
#pragma unroll
      for (int i = 0; i < 16; ++i)
        Bv[i] = Bp[(size_t)(half * 64 + tb + i) * 140];
#pragma unroll
      for (int i = 0; i < 16; ++i) {
        float sdv = lane_bcast(dv64, tb + i);
        float sdu = lane_bcast(du64, tb + i);
        float a = exp2f(sdv * A);
        Pv *= a;
        Sv = fmaf(Sv, a, sdu * Bv[i]);
      }
    }
  }
  psP[c][lane] = Pv;
  psS[c][lane] = Sv;
  __syncthreads();
  // ---- combine: h_init for this wave's chunk ----
  float h = 0.f;
  for (int k = 0; k < c; ++k)
    h = fmaf(psP[k][lane], h, psS[k][lane]);
  // ---- phase 2: replay + gated coalesced write ----
  float ddv = Dvec[d];
  float* yp = yT + ((size_t)b * 384 + d) * 1024 + t0;
  const float* xcp = xc + ((size_t)b * 1024 + t0) * 384 + d;
  const float* xzp = xz + ((size_t)b * 1024 + t0) * 768 + 384 + d;
  int tq = lane & 15;
  int q  = lane >> 4;
#pragma unroll
  for (int half = 0; half < 2; ++half) {
    float dv64 = dT[half * 64 + lane];
    float du64 = uT[half * 64 + lane];
    for (int tb = 0; tb < 64; tb += 16) {
      int ts = half * 64 + tb;
      float Bv[16], Cv[16];
#pragma unroll
      for (int i = 0; i < 16; ++i) {
        size_t ro = (size_t)(ts + i) * 140;
        Bv[i] = Bp[ro];
        Cv[i] = Cp[ro];
      }
      float xcv = 0.f, zv = 0.f;
      if (lane < 16) {
        xcv = xcp[(size_t)(ts + lane) * 384];
        zv  = xzp[(size_t)(ts + lane) * 768];
      }
#pragma unroll
      for (int i = 0; i < 16; ++i) {
        float sdv = lane_bcast(dv64, tb + i);
        float sdu = lane_bcast(du64, tb + i);
        float a = exp2f(sdv * A);
        h = fmaf(h, a, sdu * Bv[i]);
        tile[c][i][lane] = h * Cv[i];
      }
      const float* trow = &tile[c][tq][q * 16];
      float s = 0.f;
#pragma unroll
      for (int i = 0; i < 16; ++i) s += trow[i];
      s += __shfl_xor(s, 16, 64);
      s += __shfl_xor(s, 32, 64);
      if (lane < 16) {
        float sg = zv / (1.f + __expf(-zv));
        yp[ts + lane] = (s + xcv * ddv) * sg;
      }
    }
  }
}

// ---------------- radix-4 1024-pt FFT in LDS ----------------
__device__ __forceinline__ int rev4_10(int i) {
  unsigned r = __brev((unsigned)i) >> 22;
  return (int)(((r & 0x155u) << 1) | ((r >> 1) & 0x155u));
}

__device__ __forceinline__ void fft1024r4(float* __restrict__ re,
    float* __restrict__ im, const float* __restrict__ twc,
    const float* __restrict__ tws, int tid, float sgn) {
  for (int i = tid; i < 1024; i += 256) {
    int r = rev4_10(i);
    if (i < r) {
      float t = re[i]; re[i] = re[r]; re[r] = t;
      t = im[i]; im[i] = im[r]; im[r] = t;
    }
  }
  __syncthreads();
  {
    float4 ar = *(float4*)&re[tid * 4];
    float4 ai = *(float4*)&im[tid * 4];
    float apc_r = ar.x + ar.z, amc_r = ar.x - ar.z;
    float apc_i = ai.x + ai.z, amc_i = ai.x - ai.z;
    float bpd_r = ar.y + ar.w, bmd_r = ar.y - ar.w;
    float bpd_i = ai.y + ai.w, bmd_i = ai.y - ai.w;
    float4 yr, yi;
    yr.x = apc_r + bpd_r;        yi.x = apc_i + bpd_i;
    yr.z = apc_r - bpd_r;        yi.z = apc_i - bpd_i;
    yr.y = amc_r - sgn * bmd_i;  yi.y = amc_i + sgn * bmd_r;
    yr.w = amc_r + sgn * bmd_i;  yi.w = amc_i - sgn * bmd_r;
    *(float4*)&re[tid * 4] = yr;
    *(float4*)&im[tid * 4] = yi;
  }
  __syncthreads();
#pragma unroll
  for (int s = 1; s < 5; ++s) {
    int L = 1 << (2 * s);
    int tstep = 256 >> (2 * s);
    int j = tid & (L - 1);
    int base = ((tid >> (2 * s)) << (2 * s + 2)) + j;
    int i0 = base, i1 = base + L, i2 = base + 2 * L, i3 = base + 3 * L;
    int x1i = j * tstep;
    float w1c = twc[x1i],     w1s = tws[x1i];
    float w2c = twc[2 * x1i], w2s = tws[2 * x1i];
    float w3c = twc[3 * x1i], w3s = tws[3 * x1i];
    float ar_ = re[i0], ai_ = im[i0];
    float br_ = re[i1], bi_ = im[i1];
    float cr_ = re[i2], ci_ = im[i2];
    float dr_ = re[i3], di_ = im[i3];
    float tbr = br_ * w1c - bi_ * w1s, tbi = br_ * w1s + bi_ * w1c;
    float tcr = cr_ * w2c - ci_ * w2s, tci = cr_ * w2s + ci_ * w2c;
    float tdr = dr_ * w3c - di_ * w3s, tdi = dr_ * w3s + di_ * w3c;
    float apc_r = ar_ + tcr, amc_r = ar_ - tcr;
    float apc_i = ai_ + tci, amc_i = ai_ - tci;
    float bpd_r = tbr + tdr, bmd_r = tbr - tdr;
    float bpd_i = tbi + tdi, bmd_i = tbi - tdi;
    re[i0] = apc_r + bpd_r;       im[i0] = apc_i + bpd_i;
    re[i2] = apc_r - bpd_r;       im[i2] = apc_i - bpd_i;
    re[i1] = amc_r - sgn * bmd_i; im[i1] = amc_i + sgn * bmd_r;
    re[i3] = amc_r + sgn * bmd_i; im[i3] = amc_i - sgn * bmd_r;
    __syncthreads();
  }
}

// forward fft2: one block per (Bi,d,c). Inline 4-pt DFT over c on load.
__global__ __launch_bounds__(256) void fft_fwd(const float* __restrict__ xin,
    float* __restrict__ Xre, float* __restrict__ Xim) {
  __shared__ float re[1024];
  __shared__ float im[1024];
  __shared__ float twc[768];
  __shared__ float tws[768];
  int blk = blockIdx.x;
  int c = blk & 3;
  int rest = blk >> 2;
  int d = rest % 48, Bi = rest / 48;
  int tid = threadIdx.x;
  for (int k = tid; k < 768; k += 256) {
    float sv, cv;
    __sincosf(-PI_F * (float)k * (1.f / 512.f), &sv, &cv);
    twc[k] = cv; tws[k] = sv;
  }
  for (int n = tid; n < 1024; n += 256) {
    const float* p = xin + (size_t)(Bi * 1024 + n) * 192 + d;
    float v0 = p[0], v1 = p[48], v2 = p[96], v3 = p[144];
    float rr, ii;
    if (c == 0)      { rr = v0 + v1 + v2 + v3; ii = 0.f; }
    else if (c == 1) { rr = v0 - v2;           ii = -(v1 - v3); }
    else if (c == 2) { rr = v0 - v1 + v2 - v3; ii = 0.f; }
    else             { rr = v0 - v2;           ii = (v1 - v3); }
    re[n] = rr; im[n] = ii;
  }
  __syncthreads();
  fft1024r4(re, im, twc, tws, tid, -1.0f);
  for (int k = tid; k < 1024; k += 256) {
    size_t o = ((size_t)(Bi * 1024 + k) * 4 + c) * 48 + d;
    Xre[o] = re[k] * (1.f / 64.f);
    Xim[o] = im[k] * (1.f / 64.f);
  }
}

// ---------------- EinFFT frequency mix, FUSED l1+l2: one wave per row -------
// r1/i1 stay in LDS within the wave (no global round-trip, no barrier).
__global__ __launch_bounds__(256) void mix_fused(float* __restrict__ Xre,
    float* __restrict__ Xim, const float* __restrict__ cw1,
    const float* __restrict__ cw2, const float* __restrict__ cb1,
    const float* __restrict__ cb2) {
  __shared__ float r1s[4][52];
  __shared__ float i1s[4][52];
  int w = threadIdx.x >> 6;
  int j = threadIdx.x & 63;
  int row = blockIdx.x * 4 + w;
  int b = row & 3;
  const float* xr = Xre + (size_t)row * 48;
  const float* xi = Xim + (size_t)row * 48;
  if (j < 48) {
    const float* wr = cw1 + b * 2304;
    const float* wi = cw1 + 9216 + b * 2304;
    float ar = cb1[b * 48 + j];
    float ai = cb1[192 + b * 48 + j];
#pragma unroll 12
    for (int dd = 0; dd < 48; ++dd) {
      float xrv = xr[dd], xiv = xi[dd];
      float wrv = wr[dd * 48 + j], wiv = wi[dd * 48 + j];
      ar = fmaf(xrv, wrv, ar);
      ar = fmaf(-xiv, wiv, ar);
      ai = fmaf(xrv, wiv, ai);
      ai = fmaf(xiv, wrv, ai);
    }
    r1s[w][j] = fmaxf(ar, 0.f);
    i1s[w][j] = fmaxf(ai, 0.f);
    // same-wave LDS RAW: compiler inserts lgkmcnt wait, no barrier needed
    const float* wr2 = cw2 + b * 2304;
    const float* wi2 = cw2 + 9216 + b * 2304;
    float a2r = cb2[b * 48 + j];
    float a2i = cb2[192 + b * 48 + j];
#pragma unroll 12
    for (int dd = 0; dd < 48; ++dd) {
      float rv = r1s[w][dd], iv = i1s[w][dd];
      float wrv = wr2[dd * 48 + j], wiv = wi2[dd * 48 + j];
      a2r = fmaf(rv, wrv, a2r);
      a2r = fmaf(-iv, wiv, a2r);
      a2i = fmaf(rv, wiv, a2i);
      a2i = fmaf(iv, wrv, a2i);
    }
    float zr = (a2r > 0.01f) ? a2r - 0.01f : ((a2r < -0.01f) ? a2r + 0.01f : 0.f);
    float zi = (a2i > 0.01f) ? a2i - 0.01f : ((a2i < -0.01f) ? a2i + 0.01f : 0.f);
    Xre[(size_t)row * 48 + j] = zr;
    Xim[(size_t)row * 48 + j] = zi;
  }
}

// inverse fft2: one block per (Bi,d,c). Inline inverse 4-pt DFT on load,
// IFFT, add residual, write real part.
__global__ __launch_bounds__(256) void fft_inv(const float* __restrict__ Zre,
    const float* __restrict__ Zim, const float* __restrict__ x1, float* __restrict__ out) {
  __shared__ float re[1024];
  __shared__ float im[1024];
  __shared__ float twc[768];
  __shared__ float tws[768];
  int blk = blockIdx.x;
  int c = blk & 3;
  int rest = blk >> 2;
  int d = rest % 48, Bi = rest / 48;
  int tid = threadIdx.x;
  for (int k = tid; k < 768; k += 256) {
    float sv, cv;
    __sincosf(PI_F * (float)k * (1.f / 512.f), &sv, &cv);
    twc[k] = cv; tws[k] = sv;
  }
  for (int k = tid; k < 1024; k += 256) {
    size_t o = ((size_t)(Bi * 1024 + k) * 4) * 48 + d;
    float r0 = Zre[o], r1v = Zre[o + 48], r2 = Zre[o + 96], r3 = Zre[o + 144];
    float i0 = Zim[o], i1v = Zim[o + 48], i2 = Zim[o + 96], i3 = Zim[o + 144];
    float rr, ii;
    if (c == 0)      { rr = r0 + r1v + r2 + r3;  ii = i0 + i1v + i2 + i3; }
    else if (c == 1) { rr = r0 - i1v - r2 + i3;  ii = i0 + r1v - i2 - r3; }
    else if (c == 2) { rr = r0 - r1v + r2 - r3;  ii = i0 - i1v + i2 - i3; }
    else             { rr = r0 + i1v - r2 - i3;  ii = i0 - r1v - i2 + r3; }
    re[k] = rr; im[k] = ii;
  }
  __syncthreads();
  fft1024r4(re, im, twc, tws, tid, 1.0f);
  for (int n = tid; n < 1024; n += 256) {
    size_t o = (size_t)(Bi * 1024 + n) * 192 + c * 48 + d;
    out[o] = x1[o] + re[n] * (1.f / 64.f);
  }
}

extern "C" void kernel_launch(void* const* d_in, const int* in_sizes, int n_in,
                              void* d_out, int out_size, void* d_ws, size_t ws_size,
                              hipStream_t stream) {
  const float* x         = (const float*)d_in[0];
  const float* ln1_w     = (const float*)d_in[1];
  const float* ln1_b     = (const float*)d_in[2];
  const float* in_proj_w = (const float*)d_in[3];
  const float* conv_w    = (const float*)d_in[4];
  const float* conv_b    = (const float*)d_in[5];
  const float* x_proj_w  = (const float*)d_in[6];
  const float* dt_proj_w = (const float*)d_in[7];
  const float* dt_proj_b = (const float*)d_in[8];
  const float* A_log     = (const float*)d_in[9];
  const float* Dvec      = (const float*)d_in[10];
  const float* out_proj_w= (const float*)d_in[11];
  const float* ln2_w     = (const float*)d_in[12];
  const float* ln2_b     = (const float*)d_in[13];
  const float* cw1       = (const float*)d_in[14];
  const float* cw2       = (const float*)d_in[15];
  const float* cb1       = (const float*)d_in[16];
  const float* cb2       = (const float*)d_in[17];
  float* out = (float*)d_out;
  float* ws  = (float*)d_ws;

  // workspace layout (floats). Aliases:
  //  duT = Xre+Xim region (dead until fft_fwd), dltT in dlt's slot,
  //  x1 = xln (dead after in_proj consumes it).
  float* xz   = ws;                    // 3145728
  float* xc   = xz  + 3145728;         // 1572864
  float* dbc  = xc  + 1572864;         // 573440
  float* dltT = dbc + 573440;          // 1572864
  float* yvT  = dltT + 1572864;        // 1572864 (TRANSPOSED y: [b][d][t])
  float* xln  = yvT + 1572864;         // 786432
  float* x2   = xln + 786432;          // 786432
  float* Xre  = x2  + 786432;          // 786432
  float* Xim  = Xre + 786432;          // 786432
  float* duT = Xre;                    // 1572864 (spans Xre+Xim)
  float* x1 = xln;

  ln_kernel<<<1024, 256, 0, stream>>>(x, ln1_w, ln1_b, xln);
  gemm_tn<<<dim3(12, 64), 256, 0, stream>>>(xln, in_proj_w, nullptr, xz, 4096, 768, 192);
  conv_silu<<<1536, 256, 0, stream>>>(xz, conv_w, conv_b, xc);
  gemm_tn32<<<dim3(3, 128), 256, 0, stream>>>(xc, x_proj_w, nullptr, dbc, 4096, 140, 384);
  delta_trans<<<384, 256, 0, stream>>>(dbc, dt_proj_w, dt_proj_b, xc, dltT, duT);
  scan_fused<<<1536, 512, 0, stream>>>(dltT, duT, dbc, A_log, xc, xz, Dvec, yvT);
  gemm_at32<<<dim3(3, 128), 256, 0, stream>>>(yvT, out_proj_w, x, x1, 4096, 192, 384);
  ln_kernel<<<1024, 256, 0, stream>>>(x1, ln2_w, ln2_b, x2);
  fft_fwd<<<768, 256, 0, stream>>>(x2, Xre, Xim);
  mix_fused<<<4096, 256, 0, stream>>>(Xre, Xim, cw1, cw2, cb1, cb2);
  fft_inv<<<768, 256, 0, stream>>>(Xre, Xim, x1, out);
}

// Round 16
// 361.356 us; speedup vs baseline: 1.0752x; 1.0541x over previous
//
#include <hip/hip_runtime.h>
#include <math.h>

#define PI_F 3.14159265358979323846f

// broadcast lane l's value of v to all lanes (v_readlane -> SGPR)
__device__ __forceinline__ float lane_bcast(float v, int l) {
  return __int_as_float(__builtin_amdgcn_readlane(__float_as_int(v), l));
}

// ---------------- wave reduce ----------------
__device__ __forceinline__ float wave_reduce_sum(float v) {
  v += __shfl_xor(v, 32, 64);
  v += __shfl_xor(v, 16, 64);
  v += __shfl_xor(v, 8, 64);
  v += __shfl_xor(v, 4, 64);
  v += __shfl_xor(v, 2, 64);
  v += __shfl_xor(v, 1, 64);
  return v;
}

// ---------------- LayerNorm: 4 rows per 256-thread block (wave per row) ------
__global__ __launch_bounds__(256) void ln_kernel(const float* __restrict__ x,
    const float* __restrict__ w, const float* __restrict__ b, float* __restrict__ o) {
  int row = blockIdx.x * 4 + (threadIdx.x >> 6);
  int lane = threadIdx.x & 63;
  const float* xr = x + (size_t)row * 192;
  float v0 = xr[lane], v1 = xr[lane + 64], v2 = xr[lane + 128];
  float s  = wave_reduce_sum(v0 + v1 + v2);
  float s2 = wave_reduce_sum(v0 * v0 + v1 * v1 + v2 * v2);
  float mu  = s * (1.f / 192.f);
  float var = s2 * (1.f / 192.f) - mu * mu;
  float rs  = rsqrtf(var + 1e-5f);
  float* orow = o + (size_t)row * 192;
  orow[lane]       = (v0 - mu) * rs * w[lane]       + b[lane];
  orow[lane + 64]  = (v1 - mu) * rs * w[lane + 64]  + b[lane + 64];
  orow[lane + 128] = (v2 - mu) * rs * w[lane + 128] + b[lane + 128];
}

// ---------------- transposing LayerNorm: writes x2T[(Bi*192+ch)*1024 + n] ----
// 32 tokens per block via LDS tile; both global directions coalesced.
__global__ __launch_bounds__(256) void ln2t_kernel(const float* __restrict__ x,
    const float* __restrict__ w, const float* __restrict__ b, float* __restrict__ xT) {
  __shared__ float xt[32][193];
  __shared__ float mu_s[32], rs_s[32];
  int blk = blockIdx.x;            // 128 blocks
  int Bi = blk >> 5;
  int t0 = (blk & 31) * 32;
  int tid = threadIdx.x;
  const float* xb = x + ((size_t)(Bi * 1024 + t0)) * 192;
  for (int i = tid; i < 32 * 192; i += 256) {
    xt[i / 192][i % 192] = xb[i];
  }
  __syncthreads();
  int row = tid >> 3, seg = tid & 7;
  float s = 0.f, s2 = 0.f;
  const float* xr = &xt[row][seg * 24];
#pragma unroll
  for (int k = 0; k < 24; ++k) { float v = xr[k]; s += v; s2 += v * v; }
  s  += __shfl_xor(s, 1, 64);  s  += __shfl_xor(s, 2, 64);  s  += __shfl_xor(s, 4, 64);
  s2 += __shfl_xor(s2, 1, 64); s2 += __shfl_xor(s2, 2, 64); s2 += __shfl_xor(s2, 4, 64);
  if (seg == 0) {
    float mu = s * (1.f / 192.f);
    float var = s2 * (1.f / 192.f) - mu * mu;
    mu_s[row] = mu;
    rs_s[row] = rsqrtf(var + 1e-5f);
  }
  __syncthreads();
  for (int i = tid; i < 32 * 192; i += 256) {
    int ch = i >> 5, r2 = i & 31;
    float v = (xt[r2][ch] - mu_s[r2]) * rs_s[r2] * w[ch] + b[ch];
    xT[((size_t)(Bi * 192 + ch)) * 1024 + t0 + r2] = v;
  }
}

// ---------------- pipelined tiled GEMM 64x64: C = A @ W^T (+res) ----------------
__global__ __launch_bounds__(256) void gemm_tn(const float* __restrict__ A,
    const float* __restrict__ W, const float* __restrict__ res, float* __restrict__ C,
    int M, int N, int K) {
  __shared__ float As[2][32][68];   // [buf][k][m]
  __shared__ float Ws[2][32][68];   // [buf][k][n]
  int tid = threadIdx.x;
  int m0 = blockIdx.y * 64, n0 = blockIdx.x * 64;
  int tr = tid >> 4, tc = tid & 15;
  int sm  = tid >> 3;
  int skq = tid & 7;
  float4 aP[2], wP[2];
#pragma unroll
  for (int j = 0; j < 2; ++j) {
    int m = sm + j * 32;
    aP[j] = *(const float4*)(A + (size_t)(m0 + m) * K + skq * 4);
    int n = n0 + m;
    if (n < N) wP[j] = *(const float4*)(W + (size_t)n * K + skq * 4);
    else       wP[j] = make_float4(0.f, 0.f, 0.f, 0.f);
  }
#pragma unroll
  for (int j = 0; j < 2; ++j) {
    int m = sm + j * 32;
    As[0][skq * 4 + 0][m] = aP[j].x;
    As[0][skq * 4 + 1][m] = aP[j].y;
    As[0][skq * 4 + 2][m] = aP[j].z;
    As[0][skq * 4 + 3][m] = aP[j].w;
    Ws[0][skq * 4 + 0][m] = wP[j].x;
    Ws[0][skq * 4 + 1][m] = wP[j].y;
    Ws[0][skq * 4 + 2][m] = wP[j].z;
    Ws[0][skq * 4 + 3][m] = wP[j].w;
  }
  __syncthreads();
  float acc[4][4] = {{0.f}};
  int nk = K >> 5;
  for (int it = 0; it < nk; ++it) {
    int cur = it & 1, nxt = cur ^ 1;
    if (it + 1 < nk) {
      int kk = (it + 1) << 5;
#pragma unroll
      for (int j = 0; j < 2; ++j) {
        int m = sm + j * 32;
        aP[j] = *(const float4*)(A + (size_t)(m0 + m) * K + kk + skq * 4);
        int n = n0 + m;
        if (n < N) wP[j] = *(const float4*)(W + (size_t)n * K + kk + skq * 4);
        else       wP[j] = make_float4(0.f, 0.f, 0.f, 0.f);
      }
    }
#pragma unroll
    for (int k = 0; k < 32; ++k) {
      float4 a4 = *(const float4*)&As[cur][k][tr * 4];
      float4 w4 = *(const float4*)&Ws[cur][k][tc * 4];
      float a[4] = {a4.x, a4.y, a4.z, a4.w};
      float bb[4] = {w4.x, w4.y, w4.z, w4.w};
#pragma unroll
      for (int i = 0; i < 4; ++i)
#pragma unroll
        for (int j = 0; j < 4; ++j)
          acc[i][j] = fmaf(a[i], bb[j], acc[i][j]);
    }
    if (it + 1 < nk) {
#pragma unroll
      for (int j = 0; j < 2; ++j) {
        int m = sm + j * 32;
        As[nxt][skq * 4 + 0][m] = aP[j].x;
        As[nxt][skq * 4 + 1][m] = aP[j].y;
        As[nxt][skq * 4 + 2][m] = aP[j].z;
        As[nxt][skq * 4 + 3][m] = aP[j].w;
        Ws[nxt][skq * 4 + 0][m] = wP[j].x;
        Ws[nxt][skq * 4 + 1][m] = wP[j].y;
        Ws[nxt][skq * 4 + 2][m] = wP[j].z;
        Ws[nxt][skq * 4 + 3][m] = wP[j].w;
      }
      __syncthreads();
    }
  }
#pragma unroll
  for (int i = 0; i < 4; ++i) {
    int m = m0 + tr * 4 + i;
#pragma unroll
    for (int j = 0; j < 4; ++j) {
      int n = n0 + tc * 4 + j;
      if (n < N) {
        float v = acc[i][j];
        if (res) v += res[m * N + n];
        C[m * N + n] = v;
      }
    }
  }
}

// ---------------- pipelined GEMM BM=32 x BN=64 for skinny-N ----------------
__global__ __launch_bounds__(256) void gemm_tn32(const float* __restrict__ A,
    const float* __restrict__ W, const float* __restrict__ res, float* __restrict__ C,
    int M, int N, int K) {
  __shared__ float As[2][32][36];   // [buf][k][m(32)]
  __shared__ float Ws[2][32][68];   // [buf][k][n(64)]
  int tid = threadIdx.x;
  int m0 = blockIdx.y * 32, n0 = blockIdx.x * 64;
  int tr = tid >> 4, tc = tid & 15;
  int sm  = tid >> 3;
  int skq = tid & 7;
  float4 aP, wP[2];
  aP = *(const float4*)(A + (size_t)(m0 + sm) * K + skq * 4);
#pragma unroll
  for (int j = 0; j < 2; ++j) {
    int n = n0 + sm + j * 32;
    if (n < N) wP[j] = *(const float4*)(W + (size_t)n * K + skq * 4);
    else       wP[j] = make_float4(0.f, 0.f, 0.f, 0.f);
  }
  As[0][skq * 4 + 0][sm] = aP.x;
  As[0][skq * 4 + 1][sm] = aP.y;
  As[0][skq * 4 + 2][sm] = aP.z;
  As[0][skq * 4 + 3][sm] = aP.w;
#pragma unroll
  for (int j = 0; j < 2; ++j) {
    int n = sm + j * 32;
    Ws[0][skq * 4 + 0][n] = wP[j].x;
    Ws[0][skq * 4 + 1][n] = wP[j].y;
    Ws[0][skq * 4 + 2][n] = wP[j].z;
    Ws[0][skq * 4 + 3][n] = wP[j].w;
  }
  __syncthreads();
  float acc[2][4] = {{0.f}};
  int nk = K >> 5;
  for (int it = 0; it < nk; ++it) {
    int cur = it & 1, nxt = cur ^ 1;
    if (it + 1 < nk) {
      int kk = (it + 1) << 5;
      aP = *(const float4*)(A + (size_t)(m0 + sm) * K + kk + skq * 4);
#pragma unroll
      for (int j = 0; j < 2; ++j) {
        int n = n0 + sm + j * 32;
        if (n < N) wP[j] = *(const float4*)(W + (size_t)n * K + kk + skq * 4);
        else       wP[j] = make_float4(0.f, 0.f, 0.f, 0.f);
      }
    }
#pragma unroll
    for (int k = 0; k < 32; ++k) {
      float2 a2 = *(const float2*)&As[cur][k][tr * 2];
      float4 w4 = *(const float4*)&Ws[cur][k][tc * 4];
      float a[2] = {a2.x, a2.y};
      float bb[4] = {w4.x, w4.y, w4.z, w4.w};
#pragma unroll
      for (int i = 0; i < 2; ++i)
#pragma unroll
        for (int j = 0; j < 4; ++j)
          acc[i][j] = fmaf(a[i], bb[j], acc[i][j]);
    }
    if (it + 1 < nk) {
      As[nxt][skq * 4 + 0][sm] = aP.x;
      As[nxt][skq * 4 + 1][sm] = aP.y;
      As[nxt][skq * 4 + 2][sm] = aP.z;
      As[nxt][skq * 4 + 3][sm] = aP.w;
#pragma unroll
      for (int j = 0; j < 2; ++j) {
        int n = sm + j * 32;
        Ws[nxt][skq * 4 + 0][n] = wP[j].x;
        Ws[nxt][skq * 4 + 1][n] = wP[j].y;
        Ws[nxt][skq * 4 + 2][n] = wP[j].z;
        Ws[nxt][skq * 4 + 3][n] = wP[j].w;
      }
      __syncthreads();
    }
  }
#pragma unroll
  for (int i = 0; i < 2; ++i) {
    int m = m0 + tr * 2 + i;
#pragma unroll
    for (int j = 0; j < 4; ++j) {
      int n = n0 + tc * 4 + j;
      if (n < N) {
        float v = acc[i][j];
        if (res) v += res[m * N + n];
        C[m * N + n] = v;
      }
    }
  }
}

// ---------------- gemm_tn32 with TRANSPOSED A: AT[(bb*K + k)*1024 + t] ----
__global__ __launch_bounds__(256) void gemm_at32(const float* __restrict__ AT,
    const float* __restrict__ W, const float* __restrict__ res, float* __restrict__ C,
    int M, int N, int K) {
  __shared__ float As[2][32][36];   // [buf][k][m(32)]
  __shared__ float Ws[2][32][68];   // [buf][k][n(64)]
  int tid = threadIdx.x;
  int m0 = blockIdx.y * 32, n0 = blockIdx.x * 64;
  int bb = m0 >> 10;
  int t0 = m0 & 1023;
  const float* Ab = AT + ((size_t)bb * K) * 1024 + t0;
  int tr = tid >> 4, tc = tid & 15;
  int sm  = tid >> 3;
  int skq = tid & 7;
  float4 aP, wP[2];
  aP = *(const float4*)(Ab + (size_t)sm * 1024 + skq * 4);
#pragma unroll
  for (int j = 0; j < 2; ++j) {
    int n = n0 + sm + j * 32;
    if (n < N) wP[j] = *(const float4*)(W + (size_t)n * K + skq * 4);
    else       wP[j] = make_float4(0.f, 0.f, 0.f, 0.f);
  }
  *(float4*)&As[0][sm][skq * 4] = aP;
#pragma unroll
  for (int j = 0; j < 2; ++j) {
    int n = sm + j * 32;
    Ws[0][skq * 4 + 0][n] = wP[j].x;
    Ws[0][skq * 4 + 1][n] = wP[j].y;
    Ws[0][skq * 4 + 2][n] = wP[j].z;
    Ws[0][skq * 4 + 3][n] = wP[j].w;
  }
  __syncthreads();
  float acc[2][4] = {{0.f}};
  int nk = K >> 5;
  for (int it = 0; it < nk; ++it) {
    int cur = it & 1, nxt = cur ^ 1;
    if (it + 1 < nk) {
      int kk = (it + 1) << 5;
      aP = *(const float4*)(Ab + (size_t)(kk + sm) * 1024 + skq * 4);
#pragma unroll
      for (int j = 0; j < 2; ++j) {
        int n = n0 + sm + j * 32;
        if (n < N) wP[j] = *(const float4*)(W + (size_t)n * K + kk + skq * 4);
        else       wP[j] = make_float4(0.f, 0.f, 0.f, 0.f);
      }
    }
#pragma unroll
    for (int k = 0; k < 32; ++k) {
      float2 a2 = *(const float2*)&As[cur][k][tr * 2];
      float4 w4 = *(const float4*)&Ws[cur][k][tc * 4];
      float a[2] = {a2.x, a2.y};
      float bb4[4] = {w4.x, w4.y, w4.z, w4.w};
#pragma unroll
      for (int i = 0; i < 2; ++i)
#pragma unroll
        for (int j = 0; j < 4; ++j)
          acc[i][j] = fmaf(a[i], bb4[j], acc[i][j]);
    }
    if (it + 1 < nk) {
      *(float4*)&As[nxt][sm][skq * 4] = aP;
#pragma unroll
      for (int j = 0; j < 2; ++j) {
        int n = sm + j * 32;
        Ws[nxt][skq * 4 + 0][n] = wP[j].x;
        Ws[nxt][skq * 4 + 1][n] = wP[j].y;
        Ws[nxt][skq * 4 + 2][n] = wP[j].z;
        Ws[nxt][skq * 4 + 3][n] = wP[j].w;
      }
      __syncthreads();
    }
  }
#pragma unroll
  for (int i = 0; i < 2; ++i) {
    int m = m0 + tr * 2 + i;
#pragma unroll
    for (int j = 0; j < 4; ++j) {
      int n = n0 + tc * 4 + j;
      if (n < N) {
        float v = acc[i][j];
        if (res) v += res[m * N + n];
        C[m * N + n] = v;
      }
    }
  }
}

// ---------------- causal depthwise conv1d(k=4) + SiLU, float4 over d --------
__global__ __launch_bounds__(256) void conv_silu(const float* __restrict__ xz,
    const float* __restrict__ cw, const float* __restrict__ cb, float* __restrict__ xc) {
  int e4 = blockIdx.x * 256 + threadIdx.x;   // [0, 393216)
  if (e4 >= 4 * 1024 * 96) return;
  int d4 = e4 % 96;
  int t  = (e4 / 96) % 1024;
  int b  = e4 / (96 * 1024);
  int d = d4 * 4;
  const float* base = xz + (size_t)(b * 1024) * 768 + d;
  float4 acc = *(const float4*)(cb + d);
  const float4* cwv = (const float4*)(cw + d * 4);
  float4 c0 = cwv[0], c1 = cwv[1], c2 = cwv[2], c3 = cwv[3];
#pragma unroll
  for (int j = 0; j < 4; ++j) {
    int tt = t - 3 + j;
    if (tt >= 0) {
      float4 v = *(const float4*)(base + (size_t)tt * 768);
      float w0 = (&c0.x)[j], w1 = (&c1.x)[j], w2 = (&c2.x)[j], w3 = (&c3.x)[j];
      acc.x = fmaf(v.x, w0, acc.x);
      acc.y = fmaf(v.y, w1, acc.y);
      acc.z = fmaf(v.z, w2, acc.z);
      acc.w = fmaf(v.w, w3, acc.w);
    }
  }
  float4 o;
  o.x = acc.x / (1.f + __expf(-acc.x));
  o.y = acc.y / (1.f + __expf(-acc.y));
  o.z = acc.z / (1.f + __expf(-acc.z));
  o.w = acc.w / (1.f + __expf(-acc.w));
  *(float4*)(xc + ((size_t)(b * 1024 + t) * 384) + d) = o;
}

// ---------------- delta + transpose: dltT[b,d,t], duT[b,d,t] = dlt*xc ------
__global__ __launch_bounds__(256) void delta_trans(const float* __restrict__ dbc,
    const float* __restrict__ dtw, const float* __restrict__ dtb,
    const float* __restrict__ xc, float* __restrict__ dltT, float* __restrict__ duT) {
  __shared__ float dts[64][13];
  __shared__ float xt[64][65];
  int blk = blockIdx.x;           // 4 * 16 * 6 = 384
  int b  = blk / 96;
  int rem = blk % 96;
  int tt = rem / 6, dd = rem % 6;
  int t0 = tt * 64, d0 = dd * 64;
  int tid = threadIdx.x;
  for (int i = tid; i < 64 * 12; i += 256) {
    int tl = i / 12, r = i % 12;
    dts[tl][r] = dbc[((size_t)b * 1024 + t0 + tl) * 140 + r];
  }
  {
    int col = tid & 63, rg = tid >> 6;
#pragma unroll
    for (int j = 0; j < 16; ++j) {
      int row = j * 4 + rg;
      xt[row][col] = xc[((size_t)b * 1024 + t0 + row) * 384 + d0 + col];
    }
  }
  __syncthreads();
  int tl = tid & 63, grp = tid >> 6;
#pragma unroll
  for (int j = 0; j < 16; ++j) {
    int dl = grp * 16 + j;
    int d = d0 + dl;
    float s = dtb[d];
#pragma unroll
    for (int r = 0; r < 12; ++r) s += dts[tl][r] * dtw[d * 12 + r];
    float dlt = (s > 20.f) ? s : log1pf(__expf(s));
    size_t ob = ((size_t)b * 384 + d) * 1024 + t0 + tl;
    dltT[ob] = dlt;
    duT[ob]  = dlt * xt[tl][dl];
  }
}

// ---------------- FUSED selective scan (R11-proven, ~96us) ----------------
__global__ __launch_bounds__(512) void scan_fused(const float* __restrict__ dltT,
    const float* __restrict__ duT, const float* __restrict__ dbc,
    const float* __restrict__ A_log, const float* __restrict__ xc,
    const float* __restrict__ xz, const float* __restrict__ Dvec,
    float* __restrict__ yT) {
  __shared__ float tile[8][16][65];
  __shared__ float psP[8][64];
  __shared__ float psS[8][64];
  int bd = blockIdx.x;
  int b = bd / 384, d = bd % 384;
  int tid = threadIdx.x;
  int c = tid >> 6;        // wave index = chunk
  int lane = tid & 63;
  float A = -__expf(A_log[d * 64 + lane]) * 1.44269504f;
  int t0 = c * 128;
  const float* dT = dltT + ((size_t)b * 384 + d) * 1024 + t0;
  const float* uT = duT  + ((size_t)b * 384 + d) * 1024 + t0;
  const float* Bp = dbc + ((size_t)b * 1024 + t0) * 140 + 12 + lane;
  const float* Cp = Bp + 64;
  // ---- phase 1: chunk summary ----
  float Pv = 1.f, Sv = 0.f;
#pragma unroll
  for (int half = 0; half < 2; ++half) {
    float dv64 = dT[half * 64 + lane];
    float du64 = uT[half * 64 + lane];
    for (int tb = 0; tb < 64; tb += 16) {
      float Bv[16];
#pragma unroll
      for (int i = 0; i < 16; ++i)
        Bv[i] = Bp[(size_t)(half * 64 + tb + i) * 140];
#pragma unroll
      for (int i = 0; i < 16; ++i) {
        float sdv = lane_bcast(dv64, tb + i);
        float sdu = lane_bcast(du64, tb + i);
        float a = exp2f(sdv * A);
        Pv *= a;
        Sv = fmaf(Sv, a, sdu * Bv[i]);
      }
    }
  }
  psP[c][lane] = Pv;
  psS[c][lane] = Sv;
  __syncthreads();
  // ---- combine: h_init for this wave's chunk ----
  float h = 0.f;
  for (int k = 0; k < c; ++k)
    h = fmaf(psP[k][lane], h, psS[k][lane]);
  // ---- phase 2: replay + gated coalesced write ----
  float ddv = Dvec[d];
  float* yp = yT + ((size_t)b * 384 + d) * 1024 + t0;
  const float* xcp = xc + ((size_t)b * 1024 + t0) * 384 + d;
  const float* xzp = xz + ((size_t)b * 1024 + t0) * 768 + 384 + d;
  int tq = lane & 15;
  int q  = lane >> 4;
#pragma unroll
  for (int half = 0; half < 2; ++half) {
    float dv64 = dT[half * 64 + lane];
    float du64 = uT[half * 64 + lane];
    for (int tb = 0; tb < 64; tb += 16) {
      int ts = half * 64 + tb;
      float Bv[16], Cv[16];
#pragma unroll
      for (int i = 0; i < 16; ++i) {
        size_t ro = (size_t)(ts + i) * 140;
        Bv[i] = Bp[ro];
        Cv[i] = Cp[ro];
      }
      float xcv = 0.f, zv = 0.f;
      if (lane < 16) {
        xcv = xcp[(size_t)(ts + lane) * 384];
        zv  = xzp[(size_t)(ts + lane) * 768];
      }
#pragma unroll
      for (int i = 0; i < 16; ++i) {
        float sdv = lane_bcast(dv64, tb + i);
        float sdu = lane_bcast(du64, tb + i);
        float a = exp2f(sdv * A);
        h = fmaf(h, a, sdu * Bv[i]);
        tile[c][i][lane] = h * Cv[i];
      }
      const float* trow = &tile[c][tq][q * 16];
      float s = 0.f;
#pragma unroll
      for (int i = 0; i < 16; ++i) s += trow[i];
      s += __shfl_xor(s, 16, 64);
      s += __shfl_xor(s, 32, 64);
      if (lane < 16) {
        float sg = zv / (1.f + __expf(-zv));
        yp[ts + lane] = (s + xcv * ddv) * sg;
      }
    }
  }
}

// ---------------- radix-4 1024-pt FFT in LDS ----------------
__device__ __forceinline__ int rev4_10(int i) {
  unsigned r = __brev((unsigned)i) >> 22;
  return (int)(((r & 0x155u) << 1) | ((r >> 1) & 0x155u));
}

__device__ __forceinline__ void fft1024r4(float* __restrict__ re,
    float* __restrict__ im, const float* __restrict__ twc,
    const float* __restrict__ tws, int tid, float sgn) {
  for (int i = tid; i < 1024; i += 256) {
    int r = rev4_10(i);
    if (i < r) {
      float t = re[i]; re[i] = re[r]; re[r] = t;
      t = im[i]; im[i] = im[r]; im[r] = t;
    }
  }
  __syncthreads();
  {
    float4 ar = *(float4*)&re[tid * 4];
    float4 ai = *(float4*)&im[tid * 4];
    float apc_r = ar.x + ar.z, amc_r = ar.x - ar.z;
    float apc_i = ai.x + ai.z, amc_i = ai.x - ai.z;
    float bpd_r = ar.y + ar.w, bmd_r = ar.y - ar.w;
    float bpd_i = ai.y + ai.w, bmd_i = ai.y - ai.w;
    float4 yr, yi;
    yr.x = apc_r + bpd_r;        yi.x = apc_i + bpd_i;
    yr.z = apc_r - bpd_r;        yi.z = apc_i - bpd_i;
    yr.y = amc_r - sgn * bmd_i;  yi.y = amc_i + sgn * bmd_r;
    yr.w = amc_r + sgn * bmd_i;  yi.w = amc_i - sgn * bmd_r;
    *(float4*)&re[tid * 4] = yr;
    *(float4*)&im[tid * 4] = yi;
  }
  __syncthreads();
#pragma unroll
  for (int s = 1; s < 5; ++s) {
    int L = 1 << (2 * s);
    int tstep = 256 >> (2 * s);
    int j = tid & (L - 1);
    int base = ((tid >> (2 * s)) << (2 * s + 2)) + j;
    int i0 = base, i1 = base + L, i2 = base + 2 * L, i3 = base + 3 * L;
    int x1i = j * tstep;
    float w1c = twc[x1i],     w1s = tws[x1i];
    float w2c = twc[2 * x1i], w2s = tws[2 * x1i];
    float w3c = twc[3 * x1i], w3s = tws[3 * x1i];
    float ar_ = re[i0], ai_ = im[i0];
    float br_ = re[i1], bi_ = im[i1];
    float cr_ = re[i2], ci_ = im[i2];
    float dr_ = re[i3], di_ = im[i3];
    float tbr = br_ * w1c - bi_ * w1s, tbi = br_ * w1s + bi_ * w1c;
    float tcr = cr_ * w2c - ci_ * w2s, tci = cr_ * w2s + ci_ * w2c;
    float tdr = dr_ * w3c - di_ * w3s, tdi = dr_ * w3s + di_ * w3c;
    float apc_r = ar_ + tcr, amc_r = ar_ - tcr;
    float apc_i = ai_ + tci, amc_i = ai_ - tci;
    float bpd_r = tbr + tdr, bmd_r = tbr - tdr;
    float bpd_i = tbi + tdi, bmd_i = tbi - tdi;
    re[i0] = apc_r + bpd_r;       im[i0] = apc_i + bpd_i;
    re[i2] = apc_r - bpd_r;       im[i2] = apc_i - bpd_i;
    re[i1] = amc_r - sgn * bmd_i; im[i1] = amc_i + sgn * bmd_r;
    re[i3] = amc_r + sgn * bmd_i; im[i3] = amc_i - sgn * bmd_r;
    __syncthreads();
  }
}

// forward fft2: one block per (Bi,d,c). x2T channel-major -> coalesced loads;
// X stored [(Bi*4+c)*48+d][k] -> coalesced writes.
__global__ __launch_bounds__(256) void fft_fwd(const float* __restrict__ x2T,
    float* __restrict__ Xre, float* __restrict__ Xim) {
  __shared__ float re[1024];
  __shared__ float im[1024];
  __shared__ float twc[768];
  __shared__ float tws[768];
  int blk = blockIdx.x;
  int c = blk & 3;
  int rest = blk >> 2;
  int d = rest % 48, Bi = rest / 48;
  int tid = threadIdx.x;
  for (int k = tid; k < 768; k += 256) {
    float sv, cv;
    __sincosf(-PI_F * (float)k * (1.f / 512.f), &sv, &cv);
    twc[k] = cv; tws[k] = sv;
  }
  const float* pb = x2T + ((size_t)(Bi * 192 + d)) * 1024;
  for (int n = tid; n < 1024; n += 256) {
    float v0 = pb[n];
    float v1 = pb[48 * 1024 + n];
    float v2 = pb[96 * 1024 + n];
    float v3 = pb[144 * 1024 + n];
    float rr, ii;
    if (c == 0)      { rr = v0 + v1 + v2 + v3; ii = 0.f; }
    else if (c == 1) { rr = v0 - v2;           ii = -(v1 - v3); }
    else if (c == 2) { rr = v0 - v1 + v2 - v3; ii = 0.f; }
    else             { rr = v0 - v2;           ii = (v1 - v3); }
    re[n] = rr; im[n] = ii;
  }
  __syncthreads();
  fft1024r4(re, im, twc, tws, tid, -1.0f);
  float* xo_r = Xre + ((size_t)((Bi * 4 + c) * 48 + d)) * 1024;
  float* xo_i = Xim + ((size_t)((Bi * 4 + c) * 48 + d)) * 1024;
  for (int k = tid; k < 1024; k += 256) {
    xo_r[k] = re[k] * (1.f / 64.f);
    xo_i[k] = im[k] * (1.f / 64.f);
  }
}

// ---------------- EinFFT frequency mix, FUSED l1+l2: one wave per row -------
// X layout [(Bi*4+b)*48+dd][k]: reads are wave-uniform (stride-1024 broadcast),
// writes scattered (acceptable: 1.5M stores).
__global__ __launch_bounds__(256) void mix_fused(float* __restrict__ Xre,
    float* __restrict__ Xim, const float* __restrict__ cw1,
    const float* __restrict__ cw2, const float* __restrict__ cb1,
    const float* __restrict__ cb2) {
  __shared__ float r1s[4][52];
  __shared__ float i1s[4][52];
  int w = threadIdx.x >> 6;
  int j = threadIdx.x & 63;
  int row = blockIdx.x * 4 + w;          // [0, 16384)
  int b = row & 3;
  int k = (row >> 2) & 1023;
  int Bi = row >> 12;
  size_t cbase = ((size_t)((Bi * 4 + b) * 48)) * 1024 + k;
  const float* xr = Xre + cbase;
  const float* xi = Xim + cbase;
  if (j < 48) {
    const float* wr = cw1 + b * 2304;
    const float* wi = cw1 + 9216 + b * 2304;
    float ar = cb1[b * 48 + j];
    float ai = cb1[192 + b * 48 + j];
#pragma unroll 12
    for (int dd = 0; dd < 48; ++dd) {
      float xrv = xr[(size_t)dd * 1024], xiv = xi[(size_t)dd * 1024];
      float wrv = wr[dd * 48 + j], wiv = wi[dd * 48 + j];
      ar = fmaf(xrv, wrv, ar);
      ar = fmaf(-xiv, wiv, ar);
      ai = fmaf(xrv, wiv, ai);
      ai = fmaf(xiv, wrv, ai);
    }
    r1s[w][j] = fmaxf(ar, 0.f);
    i1s[w][j] = fmaxf(ai, 0.f);
    const float* wr2 = cw2 + b * 2304;
    const float* wi2 = cw2 + 9216 + b * 2304;
    float a2r = cb2[b * 48 + j];
    float a2i = cb2[192 + b * 48 + j];
#pragma unroll 12
    for (int dd = 0; dd < 48; ++dd) {
      float rv = r1s[w][dd], iv = i1s[w][dd];
      float wrv = wr2[dd * 48 + j], wiv = wi2[dd * 48 + j];
      a2r = fmaf(rv, wrv, a2r);
      a2r = fmaf(-iv, wiv, a2r);
      a2i = fmaf(rv, wiv, a2i);
      a2i = fmaf(iv, wrv, a2i);
    }
    float zr = (a2r > 0.01f) ? a2r - 0.01f : ((a2r < -0.01f) ? a2r + 0.01f : 0.f);
    float zi = (a2i > 0.01f) ? a2i - 0.01f : ((a2i < -0.01f) ? a2i + 0.01f : 0.f);
    Xre[cbase + (size_t)j * 1024] = zr;
    Xim[cbase + (size_t)j * 1024] = zi;
  }
}

// inverse fft2: one block per (Bi,d,c). Z layout [(Bi*4+c')*48+d][k] ->
// coalesced reads; inline inverse 4-pt DFT, IFFT, residual, real write.
__global__ __launch_bounds__(256) void fft_inv(const float* __restrict__ Zre,
    const float* __restrict__ Zim, const float* __restrict__ x1, float* __restrict__ out) {
  __shared__ float re[1024];
  __shared__ float im[1024];
  __shared__ float twc[768];
  __shared__ float tws[768];
  int blk = blockIdx.x;
  int c = blk & 3;
  int rest = blk >> 2;
  int d = rest % 48, Bi = rest / 48;
  int tid = threadIdx.x;
  for (int k = tid; k < 768; k += 256) {
    float sv, cv;
    __sincosf(PI_F * (float)k * (1.f / 512.f), &sv, &cv);
    twc[k] = cv; tws[k] = sv;
  }
  const float* zr0 = Zre + ((size_t)((Bi * 4) * 48 + d)) * 1024;
  const float* zi0 = Zim + ((size_t)((Bi * 4) * 48 + d)) * 1024;
  const int cs = 48 * 1024;
  for (int k = tid; k < 1024; k += 256) {
    float r0 = zr0[k], r1v = zr0[cs + k], r2 = zr0[2 * cs + k], r3 = zr0[3 * cs + k];
    float i0 = zi0[k], i1v = zi0[cs + k], i2 = zi0[2 * cs + k], i3 = zi0[3 * cs + k];
    float rr, ii;
    if (c == 0)      { rr = r0 + r1v + r2 + r3;  ii = i0 + i1v + i2 + i3; }
    else if (c == 1) { rr = r0 - i1v - r2 + i3;  ii = i0 + r1v - i2 - r3; }
    else if (c == 2) { rr = r0 - r1v + r2 - r3;  ii = i0 - i1v + i2 - i3; }
    else             { rr = r0 + i1v - r2 - i3;  ii = i0 - r1v - i2 + r3; }
    re[k] = rr; im[k] = ii;
  }
  __syncthreads();
  fft1024r4(re, im, twc, tws, tid, 1.0f);
  for (int n = tid; n < 1024; n += 256) {
    size_t o = (size_t)(Bi * 1024 + n) * 192 + c * 48 + d;
    out[o] = x1[o] + re[n] * (1.f / 64.f);
  }
}

extern "C" void kernel_launch(void* const* d_in, const int* in_sizes, int n_in,
                              void* d_out, int out_size, void* d_ws, size_t ws_size,
                              hipStream_t stream) {
  const float* x         = (const float*)d_in[0];
  const float* ln1_w     = (const float*)d_in[1];
  const float* ln1_b     = (const float*)d_in[2];
  const float* in_proj_w = (const float*)d_in[3];
  const float* conv_w    = (const float*)d_in[4];
  const float* conv_b    = (const float*)d_in[5];
  const float* x_proj_w  = (const float*)d_in[6];
  const float* dt_proj_w = (const float*)d_in[7];
  const float* dt_proj_b = (const float*)d_in[8];
  const float* A_log     = (const float*)d_in[9];
  const float* Dvec      = (const float*)d_in[10];
  const float* out_proj_w= (const float*)d_in[11];
  const float* ln2_w     = (const float*)d_in[12];
  const float* ln2_b     = (const float*)d_in[13];
  const float* cw1       = (const float*)d_in[14];
  const float* cw2       = (const float*)d_in[15];
  const float* cb1       = (const float*)d_in[16];
  const float* cb2       = (const float*)d_in[17];
  float* out = (float*)d_out;
  float* ws  = (float*)d_ws;

  // workspace layout (floats). Aliases:
  //  duT = Xre+Xim region (dead until fft_fwd), dltT in dlt's slot,
  //  x1 = xln; x2T in x2's slot (channel-major LN2 output).
  float* xz   = ws;                    // 3145728
  float* xc   = xz  + 3145728;         // 1572864
  float* dbc  = xc  + 1572864;         // 573440
  float* dltT = dbc + 573440;          // 1572864
  float* yvT  = dltT + 1572864;        // 1572864 (TRANSPOSED y: [b][d][t])
  float* xln  = yvT + 1572864;         // 786432
  float* x2T  = xln + 786432;          // 786432 (channel-major: [Bi*192+ch][n])
  float* Xre  = x2T + 786432;          // 786432 (layout [(Bi*4+c)*48+d][k])
  float* Xim  = Xre + 786432;          // 786432
  float* duT = Xre;                    // 1572864 (spans Xre+Xim)
  float* x1 = xln;

  ln_kernel<<<1024, 256, 0, stream>>>(x, ln1_w, ln1_b, xln);
  gemm_tn<<<dim3(12, 64), 256, 0, stream>>>(xln, in_proj_w, nullptr, xz, 4096, 768, 192);
  conv_silu<<<1536, 256, 0, stream>>>(xz, conv_w, conv_b, xc);
  gemm_tn32<<<dim3(3, 128), 256, 0, stream>>>(xc, x_proj_w, nullptr, dbc, 4096, 140, 384);
  delta_trans<<<384, 256, 0, stream>>>(dbc, dt_proj_w, dt_proj_b, xc, dltT, duT);
  scan_fused<<<1536, 512, 0, stream>>>(dltT, duT, dbc, A_log, xc, xz, Dvec, yvT);
  gemm_at32<<<dim3(3, 128), 256, 0, stream>>>(yvT, out_proj_w, x, x1, 4096, 192, 384);
  ln2t_kernel<<<128, 256, 0, stream>>>(x1, ln2_w, ln2_b, x2T);
  fft_fwd<<<768, 256, 0, stream>>>(x2T, Xre, Xim);
  mix_fused<<<4096, 256, 0, stream>>>(Xre, Xim, cw1, cw2, cb1, cb2);
  fft_inv<<<768, 256, 0, stream>>>(Xre, Xim, x1, out);
}

// Round 17
// 337.161 us; speedup vs baseline: 1.1524x; 1.0718x over previous
//
#include <hip/hip_runtime.h>
#include <math.h>

#define PI_F 3.14159265358979323846f

// broadcast lane l's value of v to all lanes (v_readlane -> SGPR)
__device__ __forceinline__ float lane_bcast(float v, int l) {
  return __int_as_float(__builtin_amdgcn_readlane(__float_as_int(v), l));
}

// ---------------- wave reduce ----------------
__device__ __forceinline__ float wave_reduce_sum(float v) {
  v += __shfl_xor(v, 32, 64);
  v += __shfl_xor(v, 16, 64);
  v += __shfl_xor(v, 8, 64);
  v += __shfl_xor(v, 4, 64);
  v += __shfl_xor(v, 2, 64);
  v += __shfl_xor(v, 1, 64);
  return v;
}

// ---------------- LayerNorm: 4 rows per 256-thread block (wave per row) ------
__global__ __launch_bounds__(256) void ln_kernel(const float* __restrict__ x,
    const float* __restrict__ w, const float* __restrict__ b, float* __restrict__ o) {
  int row = blockIdx.x * 4 + (threadIdx.x >> 6);
  int lane = threadIdx.x & 63;
  const float* xr = x + (size_t)row * 192;
  float v0 = xr[lane], v1 = xr[lane + 64], v2 = xr[lane + 128];
  float s  = wave_reduce_sum(v0 + v1 + v2);
  float s2 = wave_reduce_sum(v0 * v0 + v1 * v1 + v2 * v2);
  float mu  = s * (1.f / 192.f);
  float var = s2 * (1.f / 192.f) - mu * mu;
  float rs  = rsqrtf(var + 1e-5f);
  float* orow = o + (size_t)row * 192;
  orow[lane]       = (v0 - mu) * rs * w[lane]       + b[lane];
  orow[lane + 64]  = (v1 - mu) * rs * w[lane + 64]  + b[lane + 64];
  orow[lane + 128] = (v2 - mu) * rs * w[lane + 128] + b[lane + 128];
}

// ---------------- transposing LayerNorm: writes x2T[(Bi*192+ch)*1024 + n] ----
__global__ __launch_bounds__(256) void ln2t_kernel(const float* __restrict__ x,
    const float* __restrict__ w, const float* __restrict__ b, float* __restrict__ xT) {
  __shared__ float xt[32][193];
  __shared__ float mu_s[32], rs_s[32];
  int blk = blockIdx.x;            // 128 blocks
  int Bi = blk >> 5;
  int t0 = (blk & 31) * 32;
  int tid = threadIdx.x;
  const float* xb = x + ((size_t)(Bi * 1024 + t0)) * 192;
  for (int i = tid; i < 32 * 192; i += 256) {
    xt[i / 192][i % 192] = xb[i];
  }
  __syncthreads();
  int row = tid >> 3, seg = tid & 7;
  float s = 0.f, s2 = 0.f;
  const float* xr = &xt[row][seg * 24];
#pragma unroll
  for (int k = 0; k < 24; ++k) { float v = xr[k]; s += v; s2 += v * v; }
  s  += __shfl_xor(s, 1, 64);  s  += __shfl_xor(s, 2, 64);  s  += __shfl_xor(s, 4, 64);
  s2 += __shfl_xor(s2, 1, 64); s2 += __shfl_xor(s2, 2, 64); s2 += __shfl_xor(s2, 4, 64);
  if (seg == 0) {
    float mu = s * (1.f / 192.f);
    float var = s2 * (1.f / 192.f) - mu * mu;
    mu_s[row] = mu;
    rs_s[row] = rsqrtf(var + 1e-5f);
  }
  __syncthreads();
  for (int i = tid; i < 32 * 192; i += 256) {
    int ch = i >> 5, r2 = i & 31;
    float v = (xt[r2][ch] - mu_s[r2]) * rs_s[r2] * w[ch] + b[ch];
    xT[((size_t)(Bi * 192 + ch)) * 1024 + t0 + r2] = v;
  }
}

// ---------------- pipelined tiled GEMM 64x64: C = A @ W^T (+res) ----------------
__global__ __launch_bounds__(256) void gemm_tn(const float* __restrict__ A,
    const float* __restrict__ W, const float* __restrict__ res, float* __restrict__ C,
    int M, int N, int K) {
  __shared__ float As[2][32][68];   // [buf][k][m]
  __shared__ float Ws[2][32][68];   // [buf][k][n]
  int tid = threadIdx.x;
  int m0 = blockIdx.y * 64, n0 = blockIdx.x * 64;
  int tr = tid >> 4, tc = tid & 15;
  int sm  = tid >> 3;
  int skq = tid & 7;
  float4 aP[2], wP[2];
#pragma unroll
  for (int j = 0; j < 2; ++j) {
    int m = sm + j * 32;
    aP[j] = *(const float4*)(A + (size_t)(m0 + m) * K + skq * 4);
    int n = n0 + m;
    if (n < N) wP[j] = *(const float4*)(W + (size_t)n * K + skq * 4);
    else       wP[j] = make_float4(0.f, 0.f, 0.f, 0.f);
  }
#pragma unroll
  for (int j = 0; j < 2; ++j) {
    int m = sm + j * 32;
    As[0][skq * 4 + 0][m] = aP[j].x;
    As[0][skq * 4 + 1][m] = aP[j].y;
    As[0][skq * 4 + 2][m] = aP[j].z;
    As[0][skq * 4 + 3][m] = aP[j].w;
    Ws[0][skq * 4 + 0][m] = wP[j].x;
    Ws[0][skq * 4 + 1][m] = wP[j].y;
    Ws[0][skq * 4 + 2][m] = wP[j].z;
    Ws[0][skq * 4 + 3][m] = wP[j].w;
  }
  __syncthreads();
  float acc[4][4] = {{0.f}};
  int nk = K >> 5;
  for (int it = 0; it < nk; ++it) {
    int cur = it & 1, nxt = cur ^ 1;
    if (it + 1 < nk) {
      int kk = (it + 1) << 5;
#pragma unroll
      for (int j = 0; j < 2; ++j) {
        int m = sm + j * 32;
        aP[j] = *(const float4*)(A + (size_t)(m0 + m) * K + kk + skq * 4);
        int n = n0 + m;
        if (n < N) wP[j] = *(const float4*)(W + (size_t)n * K + kk + skq * 4);
        else       wP[j] = make_float4(0.f, 0.f, 0.f, 0.f);
      }
    }
#pragma unroll
    for (int k = 0; k < 32; ++k) {
      float4 a4 = *(const float4*)&As[cur][k][tr * 4];
      float4 w4 = *(const float4*)&Ws[cur][k][tc * 4];
      float a[4] = {a4.x, a4.y, a4.z, a4.w};
      float bb[4] = {w4.x, w4.y, w4.z, w4.w};
#pragma unroll
      for (int i = 0; i < 4; ++i)
#pragma unroll
        for (int j = 0; j < 4; ++j)
          acc[i][j] = fmaf(a[i], bb[j], acc[i][j]);
    }
    if (it + 1 < nk) {
#pragma unroll
      for (int j = 0; j < 2; ++j) {
        int m = sm + j * 32;
        As[nxt][skq * 4 + 0][m] = aP[j].x;
        As[nxt][skq * 4 + 1][m] = aP[j].y;
        As[nxt][skq * 4 + 2][m] = aP[j].z;
        As[nxt][skq * 4 + 3][m] = aP[j].w;
        Ws[nxt][skq * 4 + 0][m] = wP[j].x;
        Ws[nxt][skq * 4 + 1][m] = wP[j].y;
        Ws[nxt][skq * 4 + 2][m] = wP[j].z;
        Ws[nxt][skq * 4 + 3][m] = wP[j].w;
      }
      __syncthreads();
    }
  }
#pragma unroll
  for (int i = 0; i < 4; ++i) {
    int m = m0 + tr * 4 + i;
#pragma unroll
    for (int j = 0; j < 4; ++j) {
      int n = n0 + tc * 4 + j;
      if (n < N) {
        float v = acc[i][j];
        if (res) v += res[m * N + n];
        C[m * N + n] = v;
      }
    }
  }
}

// ---------------- pipelined GEMM BM=32 x BN=64 for skinny-N ----------------
__global__ __launch_bounds__(256) void gemm_tn32(const float* __restrict__ A,
    const float* __restrict__ W, const float* __restrict__ res, float* __restrict__ C,
    int M, int N, int K) {
  __shared__ float As[2][32][36];   // [buf][k][m(32)]
  __shared__ float Ws[2][32][68];   // [buf][k][n(64)]
  int tid = threadIdx.x;
  int m0 = blockIdx.y * 32, n0 = blockIdx.x * 64;
  int tr = tid >> 4, tc = tid & 15;
  int sm  = tid >> 3;
  int skq = tid & 7;
  float4 aP, wP[2];
  aP = *(const float4*)(A + (size_t)(m0 + sm) * K + skq * 4);
#pragma unroll
  for (int j = 0; j < 2; ++j) {
    int n = n0 + sm + j * 32;
    if (n < N) wP[j] = *(const float4*)(W + (size_t)n * K + skq * 4);
    else       wP[j] = make_float4(0.f, 0.f, 0.f, 0.f);
  }
  As[0][skq * 4 + 0][sm] = aP.x;
  As[0][skq * 4 + 1][sm] = aP.y;
  As[0][skq * 4 + 2][sm] = aP.z;
  As[0][skq * 4 + 3][sm] = aP.w;
#pragma unroll
  for (int j = 0; j < 2; ++j) {
    int n = sm + j * 32;
    Ws[0][skq * 4 + 0][n] = wP[j].x;
    Ws[0][skq * 4 + 1][n] = wP[j].y;
    Ws[0][skq * 4 + 2][n] = wP[j].z;
    Ws[0][skq * 4 + 3][n] = wP[j].w;
  }
  __syncthreads();
  float acc[2][4] = {{0.f}};
  int nk = K >> 5;
  for (int it = 0; it < nk; ++it) {
    int cur = it & 1, nxt = cur ^ 1;
    if (it + 1 < nk) {
      int kk = (it + 1) << 5;
      aP = *(const float4*)(A + (size_t)(m0 + sm) * K + kk + skq * 4);
#pragma unroll
      for (int j = 0; j < 2; ++j) {
        int n = n0 + sm + j * 32;
        if (n < N) wP[j] = *(const float4*)(W + (size_t)n * K + kk + skq * 4);
        else       wP[j] = make_float4(0.f, 0.f, 0.f, 0.f);
      }
    }
#pragma unroll
    for (int k = 0; k < 32; ++k) {
      float2 a2 = *(const float2*)&As[cur][k][tr * 2];
      float4 w4 = *(const float4*)&Ws[cur][k][tc * 4];
      float a[2] = {a2.x, a2.y};
      float bb[4] = {w4.x, w4.y, w4.z, w4.w};
#pragma unroll
      for (int i = 0; i < 2; ++i)
#pragma unroll
        for (int j = 0; j < 4; ++j)
          acc[i][j] = fmaf(a[i], bb[j], acc[i][j]);
    }
    if (it + 1 < nk) {
      As[nxt][skq * 4 + 0][sm] = aP.x;
      As[nxt][skq * 4 + 1][sm] = aP.y;
      As[nxt][skq * 4 + 2][sm] = aP.z;
      As[nxt][skq * 4 + 3][sm] = aP.w;
#pragma unroll
      for (int j = 0; j < 2; ++j) {
        int n = sm + j * 32;
        Ws[nxt][skq * 4 + 0][n] = wP[j].x;
        Ws[nxt][skq * 4 + 1][n] = wP[j].y;
        Ws[nxt][skq * 4 + 2][n] = wP[j].z;
        Ws[nxt][skq * 4 + 3][n] = wP[j].w;
      }
      __syncthreads();
    }
  }
#pragma unroll
  for (int i = 0; i < 2; ++i) {
    int m = m0 + tr * 2 + i;
#pragma unroll
    for (int j = 0; j < 4; ++j) {
      int n = n0 + tc * 4 + j;
      if (n < N) {
        float v = acc[i][j];
        if (res) v += res[m * N + n];
        C[m * N + n] = v;
      }
    }
  }
}

// ---------------- gemm_tn32 with TRANSPOSED A: AT[(bb*K + k)*1024 + t] ----
__global__ __launch_bounds__(256) void gemm_at32(const float* __restrict__ AT,
    const float* __restrict__ W, const float* __restrict__ res, float* __restrict__ C,
    int M, int N, int K) {
  __shared__ float As[2][32][36];   // [buf][k][m(32)]
  __shared__ float Ws[2][32][68];   // [buf][k][n(64)]
  int tid = threadIdx.x;
  int m0 = blockIdx.y * 32, n0 = blockIdx.x * 64;
  int bb = m0 >> 10;
  int t0 = m0 & 1023;
  const float* Ab = AT + ((size_t)bb * K) * 1024 + t0;
  int tr = tid >> 4, tc = tid & 15;
  int sm  = tid >> 3;
  int skq = tid & 7;
  float4 aP, wP[2];
  aP = *(const float4*)(Ab + (size_t)sm * 1024 + skq * 4);
#pragma unroll
  for (int j = 0; j < 2; ++j) {
    int n = n0 + sm + j * 32;
    if (n < N) wP[j] = *(const float4*)(W + (size_t)n * K + skq * 4);
    else       wP[j] = make_float4(0.f, 0.f, 0.f, 0.f);
  }
  *(float4*)&As[0][sm][skq * 4] = aP;
#pragma unroll
  for (int j = 0; j < 2; ++j) {
    int n = sm + j * 32;
    Ws[0][skq * 4 + 0][n] = wP[j].x;
    Ws[0][skq * 4 + 1][n] = wP[j].y;
    Ws[0][skq * 4 + 2][n] = wP[j].z;
    Ws[0][skq * 4 + 3][n] = wP[j].w;
  }
  __syncthreads();
  float acc[2][4] = {{0.f}};
  int nk = K >> 5;
  for (int it = 0; it < nk; ++it) {
    int cur = it & 1, nxt = cur ^ 1;
    if (it + 1 < nk) {
      int kk = (it + 1) << 5;
      aP = *(const float4*)(Ab + (size_t)(kk + sm) * 1024 + skq * 4);
#pragma unroll
      for (int j = 0; j < 2; ++j) {
        int n = n0 + sm + j * 32;
        if (n < N) wP[j] = *(const float4*)(W + (size_t)n * K + kk + skq * 4);
        else       wP[j] = make_float4(0.f, 0.f, 0.f, 0.f);
      }
    }
#pragma unroll
    for (int k = 0; k < 32; ++k) {
      float2 a2 = *(const float2*)&As[cur][k][tr * 2];
      float4 w4 = *(const float4*)&Ws[cur][k][tc * 4];
      float a[2] = {a2.x, a2.y};
      float bb4[4] = {w4.x, w4.y, w4.z, w4.w};
#pragma unroll
      for (int i = 0; i < 2; ++i)
#pragma unroll
        for (int j = 0; j < 4; ++j)
          acc[i][j] = fmaf(a[i], bb4[j], acc[i][j]);
    }
    if (it + 1 < nk) {
      *(float4*)&As[nxt][sm][skq * 4] = aP;
#pragma unroll
      for (int j = 0; j < 2; ++j) {
        int n = sm + j * 32;
        Ws[nxt][skq * 4 + 0][n] = wP[j].x;
        Ws[nxt][skq * 4 + 1][n] = wP[j].y;
        Ws[nxt][skq * 4 + 2][n] = wP[j].z;
        Ws[nxt][skq * 4 + 3][n] = wP[j].w;
      }
      __syncthreads();
    }
  }
#pragma unroll
  for (int i = 0; i < 2; ++i) {
    int m = m0 + tr * 2 + i;
#pragma unroll
    for (int j = 0; j < 4; ++j) {
      int n = n0 + tc * 4 + j;
      if (n < N) {
        float v = acc[i][j];
        if (res) v += res[m * N + n];
        C[m * N + n] = v;
      }
    }
  }
}

// ---------------- causal depthwise conv1d(k=4) + SiLU, float4 over d --------
__global__ __launch_bounds__(256) void conv_silu(const float* __restrict__ xz,
    const float* __restrict__ cw, const float* __restrict__ cb, float* __restrict__ xc) {
  int e4 = blockIdx.x * 256 + threadIdx.x;   // [0, 393216)
  if (e4 >= 4 * 1024 * 96) return;
  int d4 = e4 % 96;
  int t  = (e4 / 96) % 1024;
  int b  = e4 / (96 * 1024);
  int d = d4 * 4;
  const float* base = xz + (size_t)(b * 1024) * 768 + d;
  float4 acc = *(const float4*)(cb + d);
  const float4* cwv = (const float4*)(cw + d * 4);
  float4 c0 = cwv[0], c1 = cwv[1], c2 = cwv[2], c3 = cwv[3];
#pragma unroll
  for (int j = 0; j < 4; ++j) {
    int tt = t - 3 + j;
    if (tt >= 0) {
      float4 v = *(const float4*)(base + (size_t)tt * 768);
      float w0 = (&c0.x)[j], w1 = (&c1.x)[j], w2 = (&c2.x)[j], w3 = (&c3.x)[j];
      acc.x = fmaf(v.x, w0, acc.x);
      acc.y = fmaf(v.y, w1, acc.y);
      acc.z = fmaf(v.z, w2, acc.z);
      acc.w = fmaf(v.w, w3, acc.w);
    }
  }
  float4 o;
  o.x = acc.x / (1.f + __expf(-acc.x));
  o.y = acc.y / (1.f + __expf(-acc.y));
  o.z = acc.z / (1.f + __expf(-acc.z));
  o.w = acc.w / (1.f + __expf(-acc.w));
  *(float4*)(xc + ((size_t)(b * 1024 + t) * 384) + d) = o;
}

// ---------------- delta + transpose: dltT[b,d,t], duT[b,d,t] = dlt*xc ------
__global__ __launch_bounds__(256) void delta_trans(const float* __restrict__ dbc,
    const float* __restrict__ dtw, const float* __restrict__ dtb,
    const float* __restrict__ xc, float* __restrict__ dltT, float* __restrict__ duT) {
  __shared__ float dts[64][13];
  __shared__ float xt[64][65];
  int blk = blockIdx.x;           // 4 * 16 * 6 = 384
  int b  = blk / 96;
  int rem = blk % 96;
  int tt = rem / 6, dd = rem % 6;
  int t0 = tt * 64, d0 = dd * 64;
  int tid = threadIdx.x;
  for (int i = tid; i < 64 * 12; i += 256) {
    int tl = i / 12, r = i % 12;
    dts[tl][r] = dbc[((size_t)b * 1024 + t0 + tl) * 140 + r];
  }
  {
    int col = tid & 63, rg = tid >> 6;
#pragma unroll
    for (int j = 0; j < 16; ++j) {
      int row = j * 4 + rg;
      xt[row][col] = xc[((size_t)b * 1024 + t0 + row) * 384 + d0 + col];
    }
  }
  __syncthreads();
  int tl = tid & 63, grp = tid >> 6;
#pragma unroll
  for (int j = 0; j < 16; ++j) {
    int dl = grp * 16 + j;
    int d = d0 + dl;
    float s = dtb[d];
#pragma unroll
    for (int r = 0; r < 12; ++r) s += dts[tl][r] * dtw[d * 12 + r];
    float dlt = (s > 20.f) ? s : log1pf(__expf(s));
    size_t ob = ((size_t)b * 384 + d) * 1024 + t0 + tl;
    dltT[ob] = dlt;
    duT[ob]  = dlt * xt[tl][dl];
  }
}

// ---------------- FUSED selective scan (R11-proven, ~96us) ----------------
__global__ __launch_bounds__(512) void scan_fused(const float* __restrict__ dltT,
    const float* __restrict__ duT, const float* __restrict__ dbc,
    const float* __restrict__ A_log, const float* __restrict__ xc,
    const float* __restrict__ xz, const float* __restrict__ Dvec,
    float* __restrict__ yT) {
  __shared__ float tile[8][16][65];
  __shared__ float psP[8][64];
  __shared__ float psS[8][64];
  int bd = blockIdx.x;
  int b = bd / 384, d = bd % 384;
  int tid = threadIdx.x;
  int c = tid >> 6;        // wave index = chunk
  int lane = tid & 63;
  float A = -__expf(A_log[d * 64 + lane]) * 1.44269504f;
  int t0 = c * 128;
  const float* dT = dltT + ((size_t)b * 384 + d) * 1024 + t0;
  const float* uT = duT  + ((size_t)b * 384 + d) * 1024 + t0;
  const float* Bp = dbc + ((size_t)b * 1024 + t0) * 140 + 12 + lane;
  const float* Cp = Bp + 64;
  // ---- phase 1: chunk summary ----
  float Pv = 1.f, Sv = 0.f;
#pragma unroll
  for (int half = 0; half < 2; ++half) {
    float dv64 = dT[half * 64 + lane];
    float du64 = uT[half * 64 + lane];
    for (int tb = 0; tb < 64; tb += 16) {
      float Bv[16];
#pragma unroll
      for (int i = 0; i < 16; ++i)
        Bv[i] = Bp[(size_t)(half * 64 + tb + i) * 140];
#pragma unroll
      for (int i = 0; i < 16; ++i) {
        float sdv = lane_bcast(dv64, tb + i);
        float sdu = lane_bcast(du64, tb + i);
        float a = exp2f(sdv * A);
        Pv *= a;
        Sv = fmaf(Sv, a, sdu * Bv[i]);
      }
    }
  }
  psP[c][lane] = Pv;
  psS[c][lane] = Sv;
  __syncthreads();
  // ---- combine: h_init for this wave's chunk ----
  float h = 0.f;
  for (int k = 0; k < c; ++k)
    h = fmaf(psP[k][lane], h, psS[k][lane]);
  // ---- phase 2: replay + gated coalesced write ----
  float ddv = Dvec[d];
  float* yp = yT + ((size_t)b * 384 + d) * 1024 + t0;
  const float* xcp = xc + ((size_t)b * 1024 + t0) * 384 + d;
  const float* xzp = xz + ((size_t)b * 1024 + t0) * 768 + 384 + d;
  int tq = lane & 15;
  int q  = lane >> 4;
#pragma unroll
  for (int half = 0; half < 2; ++half) {
    float dv64 = dT[half * 64 + lane];
    float du64 = uT[half * 64 + lane];
    for (int tb = 0; tb < 64; tb += 16) {
      int ts = half * 64 + tb;
      float Bv[16], Cv[16];
#pragma unroll
      for (int i = 0; i < 16; ++i) {
        size_t ro = (size_t)(ts + i) * 140;
        Bv[i] = Bp[ro];
        Cv[i] = Cp[ro];
      }
      float xcv = 0.f, zv = 0.f;
      if (lane < 16) {
        xcv = xcp[(size_t)(ts + lane) * 384];
        zv  = xzp[(size_t)(ts + lane) * 768];
      }
#pragma unroll
      for (int i = 0; i < 16; ++i) {
        float sdv = lane_bcast(dv64, tb + i);
        float sdu = lane_bcast(du64, tb + i);
        float a = exp2f(sdv * A);
        h = fmaf(h, a, sdu * Bv[i]);
        tile[c][i][lane] = h * Cv[i];
      }
      const float* trow = &tile[c][tq][q * 16];
      float s = 0.f;
#pragma unroll
      for (int i = 0; i < 16; ++i) s += trow[i];
      s += __shfl_xor(s, 16, 64);
      s += __shfl_xor(s, 32, 64);
      if (lane < 16) {
        float sg = zv / (1.f + __expf(-zv));
        yp[ts + lane] = (s + xcv * ddv) * sg;
      }
    }
  }
}

// ---------------- radix-4 1024-pt FFT in LDS ----------------
__device__ __forceinline__ int rev4_10(int i) {
  unsigned r = __brev((unsigned)i) >> 22;
  return (int)(((r & 0x155u) << 1) | ((r >> 1) & 0x155u));
}

__device__ __forceinline__ void fft1024r4(float* __restrict__ re,
    float* __restrict__ im, const float* __restrict__ twc,
    const float* __restrict__ tws, int tid, float sgn) {
  for (int i = tid; i < 1024; i += 256) {
    int r = rev4_10(i);
    if (i < r) {
      float t = re[i]; re[i] = re[r]; re[r] = t;
      t = im[i]; im[i] = im[r]; im[r] = t;
    }
  }
  __syncthreads();
  {
    float4 ar = *(float4*)&re[tid * 4];
    float4 ai = *(float4*)&im[tid * 4];
    float apc_r = ar.x + ar.z, amc_r = ar.x - ar.z;
    float apc_i = ai.x + ai.z, amc_i = ai.x - ai.z;
    float bpd_r = ar.y + ar.w, bmd_r = ar.y - ar.w;
    float bpd_i = ai.y + ai.w, bmd_i = ai.y - ai.w;
    float4 yr, yi;
    yr.x = apc_r + bpd_r;        yi.x = apc_i + bpd_i;
    yr.z = apc_r - bpd_r;        yi.z = apc_i - bpd_i;
    yr.y = amc_r - sgn * bmd_i;  yi.y = amc_i + sgn * bmd_r;
    yr.w = amc_r + sgn * bmd_i;  yi.w = amc_i - sgn * bmd_r;
    *(float4*)&re[tid * 4] = yr;
    *(float4*)&im[tid * 4] = yi;
  }
  __syncthreads();
#pragma unroll
  for (int s = 1; s < 5; ++s) {
    int L = 1 << (2 * s);
    int tstep = 256 >> (2 * s);
    int j = tid & (L - 1);
    int base = ((tid >> (2 * s)) << (2 * s + 2)) + j;
    int i0 = base, i1 = base + L, i2 = base + 2 * L, i3 = base + 3 * L;
    int x1i = j * tstep;
    float w1c = twc[x1i],     w1s = tws[x1i];
    float w2c = twc[2 * x1i], w2s = tws[2 * x1i];
    float w3c = twc[3 * x1i], w3s = tws[3 * x1i];
    float ar_ = re[i0], ai_ = im[i0];
    float br_ = re[i1], bi_ = im[i1];
    float cr_ = re[i2], ci_ = im[i2];
    float dr_ = re[i3], di_ = im[i3];
    float tbr = br_ * w1c - bi_ * w1s, tbi = br_ * w1s + bi_ * w1c;
    float tcr = cr_ * w2c - ci_ * w2s, tci = cr_ * w2s + ci_ * w2c;
    float tdr = dr_ * w3c - di_ * w3s, tdi = dr_ * w3s + di_ * w3c;
    float apc_r = ar_ + tcr, amc_r = ar_ - tcr;
    float apc_i = ai_ + tci, amc_i = ai_ - tci;
    float bpd_r = tbr + tdr, bmd_r = tbr - tdr;
    float bpd_i = tbi + tdi, bmd_i = tbi - tdi;
    re[i0] = apc_r + bpd_r;       im[i0] = apc_i + bpd_i;
    re[i2] = apc_r - bpd_r;       im[i2] = apc_i - bpd_i;
    re[i1] = amc_r - sgn * bmd_i; im[i1] = amc_i + sgn * bmd_r;
    re[i3] = amc_r + sgn * bmd_i; im[i3] = amc_i - sgn * bmd_r;
    __syncthreads();
  }
}

// forward fft2: one block per (Bi,d,c). x2T channel-major -> coalesced loads;
// X stored [(Bi*4+c)*48+d][k] -> coalesced writes.
__global__ __launch_bounds__(256) void fft_fwd(const float* __restrict__ x2T,
    float* __restrict__ Xre, float* __restrict__ Xim) {
  __shared__ float re[1024];
  __shared__ float im[1024];
  __shared__ float twc[768];
  __shared__ float tws[768];
  int blk = blockIdx.x;
  int c = blk & 3;
  int rest = blk >> 2;
  int d = rest % 48, Bi = rest / 48;
  int tid = threadIdx.x;
  for (int k = tid; k < 768; k += 256) {
    float sv, cv;
    __sincosf(-PI_F * (float)k * (1.f / 512.f), &sv, &cv);
    twc[k] = cv; tws[k] = sv;
  }
  const float* pb = x2T + ((size_t)(Bi * 192 + d)) * 1024;
  for (int n = tid; n < 1024; n += 256) {
    float v0 = pb[n];
    float v1 = pb[48 * 1024 + n];
    float v2 = pb[96 * 1024 + n];
    float v3 = pb[144 * 1024 + n];
    float rr, ii;
    if (c == 0)      { rr = v0 + v1 + v2 + v3; ii = 0.f; }
    else if (c == 1) { rr = v0 - v2;           ii = -(v1 - v3); }
    else if (c == 2) { rr = v0 - v1 + v2 - v3; ii = 0.f; }
    else             { rr = v0 - v2;           ii = (v1 - v3); }
    re[n] = rr; im[n] = ii;
  }
  __syncthreads();
  fft1024r4(re, im, twc, tws, tid, -1.0f);
  float* xo_r = Xre + ((size_t)((Bi * 4 + c) * 48 + d)) * 1024;
  float* xo_i = Xim + ((size_t)((Bi * 4 + c) * 48 + d)) * 1024;
  for (int k = tid; k < 1024; k += 256) {
    xo_r[k] = re[k] * (1.f / 64.f);
    xo_i[k] = im[k] * (1.f / 64.f);
  }
}

// ---------------- EinFFT mix, FUSED l1+l2, 4 k-rows per wave ----------------
// Weights loaded once per 4 rows (L2 traffic /4); X read as wave-uniform
// float4 broadcasts over consecutive k; r1/i1 transit LDS as [dd][4] float4s
// (broadcast reads); Z written as per-lane float4 (full sectors).
__global__ __launch_bounds__(256) void mix_fused(float* __restrict__ Xre,
    float* __restrict__ Xim, const float* __restrict__ cw1,
    const float* __restrict__ cw2, const float* __restrict__ cb1,
    const float* __restrict__ cb2) {
  __shared__ float r1s[4][48][4];
  __shared__ float i1s[4][48][4];
  int w = threadIdx.x >> 6;
  int j = threadIdx.x & 63;
  int rg = blockIdx.x * 4 + w;       // [0, 4096)
  int kq = rg & 255;
  int b  = (rg >> 8) & 3;
  int Bi = rg >> 10;
  int k0 = kq * 4;
  size_t xbase = ((size_t)((Bi * 4 + b) * 48)) * 1024 + k0;
  if (j < 48) {
    const float* wr = cw1 + b * 2304;
    const float* wi = cw1 + 9216 + b * 2304;
    float b1r = cb1[b * 48 + j], b1i = cb1[192 + b * 48 + j];
    float ar[4] = {b1r, b1r, b1r, b1r};
    float ai[4] = {b1i, b1i, b1i, b1i};
#pragma unroll 8
    for (int dd = 0; dd < 48; ++dd) {
      float4 xr = *(const float4*)(Xre + xbase + (size_t)dd * 1024);
      float4 xi = *(const float4*)(Xim + xbase + (size_t)dd * 1024);
      float wrv = wr[dd * 48 + j], wiv = wi[dd * 48 + j];
      ar[0] = fmaf(xr.x, wrv, ar[0]); ar[0] = fmaf(-xi.x, wiv, ar[0]);
      ai[0] = fmaf(xr.x, wiv, ai[0]); ai[0] = fmaf(xi.x, wrv, ai[0]);
      ar[1] = fmaf(xr.y, wrv, ar[1]); ar[1] = fmaf(-xi.y, wiv, ar[1]);
      ai[1] = fmaf(xr.y, wiv, ai[1]); ai[1] = fmaf(xi.y, wrv, ai[1]);
      ar[2] = fmaf(xr.z, wrv, ar[2]); ar[2] = fmaf(-xi.z, wiv, ar[2]);
      ai[2] = fmaf(xr.z, wiv, ai[2]); ai[2] = fmaf(xi.z, wrv, ai[2]);
      ar[3] = fmaf(xr.w, wrv, ar[3]); ar[3] = fmaf(-xi.w, wiv, ar[3]);
      ai[3] = fmaf(xr.w, wiv, ai[3]); ai[3] = fmaf(xi.w, wrv, ai[3]);
    }
    float4 r1v, i1v;
    r1v.x = fmaxf(ar[0], 0.f); r1v.y = fmaxf(ar[1], 0.f);
    r1v.z = fmaxf(ar[2], 0.f); r1v.w = fmaxf(ar[3], 0.f);
    i1v.x = fmaxf(ai[0], 0.f); i1v.y = fmaxf(ai[1], 0.f);
    i1v.z = fmaxf(ai[2], 0.f); i1v.w = fmaxf(ai[3], 0.f);
    *(float4*)&r1s[w][j][0] = r1v;
    *(float4*)&i1s[w][j][0] = i1v;
    // same-wave LDS RAW: compiler inserts lgkmcnt wait; no barrier needed
    const float* wr2 = cw2 + b * 2304;
    const float* wi2 = cw2 + 9216 + b * 2304;
    float b2r = cb2[b * 48 + j], b2i = cb2[192 + b * 48 + j];
    float a2r[4] = {b2r, b2r, b2r, b2r};
    float a2i[4] = {b2i, b2i, b2i, b2i};
#pragma unroll 8
    for (int dd = 0; dd < 48; ++dd) {
      float4 rv = *(const float4*)&r1s[w][dd][0];
      float4 iv = *(const float4*)&i1s[w][dd][0];
      float wrv = wr2[dd * 48 + j], wiv = wi2[dd * 48 + j];
      a2r[0] = fmaf(rv.x, wrv, a2r[0]); a2r[0] = fmaf(-iv.x, wiv, a2r[0]);
      a2i[0] = fmaf(rv.x, wiv, a2i[0]); a2i[0] = fmaf(iv.x, wrv, a2i[0]);
      a2r[1] = fmaf(rv.y, wrv, a2r[1]); a2r[1] = fmaf(-iv.y, wiv, a2r[1]);
      a2i[1] = fmaf(rv.y, wiv, a2i[1]); a2i[1] = fmaf(iv.y, wrv, a2i[1]);
      a2r[2] = fmaf(rv.z, wrv, a2r[2]); a2r[2] = fmaf(-iv.z, wiv, a2r[2]);
      a2i[2] = fmaf(rv.z, wiv, a2i[2]); a2i[2] = fmaf(iv.z, wrv, a2i[2]);
      a2r[3] = fmaf(rv.w, wrv, a2r[3]); a2r[3] = fmaf(-iv.w, wiv, a2r[3]);
      a2i[3] = fmaf(rv.w, wiv, a2i[3]); a2i[3] = fmaf(iv.w, wrv, a2i[3]);
    }
    float4 zr, zi;
#pragma unroll
    for (int r = 0; r < 4; ++r) {
      float vr = a2r[r], vi = a2i[r];
      (&zr.x)[r] = (vr > 0.01f) ? vr - 0.01f : ((vr < -0.01f) ? vr + 0.01f : 0.f);
      (&zi.x)[r] = (vi > 0.01f) ? vi - 0.01f : ((vi < -0.01f) ? vi + 0.01f : 0.f);
    }
    size_t obase = ((size_t)((Bi * 4 + b) * 48 + j)) * 1024 + k0;
    *(float4*)(Xre + obase) = zr;
    *(float4*)(Xim + obase) = zi;
  }
}

// inverse fft2: one block per (Bi,d,c). Z layout [(Bi*4+c')*48+d][k] ->
// coalesced reads; inline inverse 4-pt DFT, IFFT, residual, real write.
__global__ __launch_bounds__(256) void fft_inv(const float* __restrict__ Zre,
    const float* __restrict__ Zim, const float* __restrict__ x1, float* __restrict__ out) {
  __shared__ float re[1024];
  __shared__ float im[1024];
  __shared__ float twc[768];
  __shared__ float tws[768];
  int blk = blockIdx.x;
  int c = blk & 3;
  int rest = blk >> 2;
  int d = rest % 48, Bi = rest / 48;
  int tid = threadIdx.x;
  for (int k = tid; k < 768; k += 256) {
    float sv, cv;
    __sincosf(PI_F * (float)k * (1.f / 512.f), &sv, &cv);
    twc[k] = cv; tws[k] = sv;
  }
  const float* zr0 = Zre + ((size_t)((Bi * 4) * 48 + d)) * 1024;
  const float* zi0 = Zim + ((size_t)((Bi * 4) * 48 + d)) * 1024;
  const int cs = 48 * 1024;
  for (int k = tid; k < 1024; k += 256) {
    float r0 = zr0[k], r1v = zr0[cs + k], r2 = zr0[2 * cs + k], r3 = zr0[3 * cs + k];
    float i0 = zi0[k], i1v = zi0[cs + k], i2 = zi0[2 * cs + k], i3 = zi0[3 * cs + k];
    float rr, ii;
    if (c == 0)      { rr = r0 + r1v + r2 + r3;  ii = i0 + i1v + i2 + i3; }
    else if (c == 1) { rr = r0 - i1v - r2 + i3;  ii = i0 + r1v - i2 - r3; }
    else if (c == 2) { rr = r0 - r1v + r2 - r3;  ii = i0 - i1v + i2 - i3; }
    else             { rr = r0 + i1v - r2 - i3;  ii = i0 - r1v - i2 + r3; }
    re[k] = rr; im[k] = ii;
  }
  __syncthreads();
  fft1024r4(re, im, twc, tws, tid, 1.0f);
  for (int n = tid; n < 1024; n += 256) {
    size_t o = (size_t)(Bi * 1024 + n) * 192 + c * 48 + d;
    out[o] = x1[o] + re[n] * (1.f / 64.f);
  }
}

extern "C" void kernel_launch(void* const* d_in, const int* in_sizes, int n_in,
                              void* d_out, int out_size, void* d_ws, size_t ws_size,
                              hipStream_t stream) {
  const float* x         = (const float*)d_in[0];
  const float* ln1_w     = (const float*)d_in[1];
  const float* ln1_b     = (const float*)d_in[2];
  const float* in_proj_w = (const float*)d_in[3];
  const float* conv_w    = (const float*)d_in[4];
  const float* conv_b    = (const float*)d_in[5];
  const float* x_proj_w  = (const float*)d_in[6];
  const float* dt_proj_w = (const float*)d_in[7];
  const float* dt_proj_b = (const float*)d_in[8];
  const float* A_log     = (const float*)d_in[9];
  const float* Dvec      = (const float*)d_in[10];
  const float* out_proj_w= (const float*)d_in[11];
  const float* ln2_w     = (const float*)d_in[12];
  const float* ln2_b     = (const float*)d_in[13];
  const float* cw1       = (const float*)d_in[14];
  const float* cw2       = (const float*)d_in[15];
  const float* cb1       = (const float*)d_in[16];
  const float* cb2       = (const float*)d_in[17];
  float* out = (float*)d_out;
  float* ws  = (float*)d_ws;

  // workspace layout (floats). Aliases:
  //  duT = Xre+Xim region (dead until fft_fwd), dltT in dlt's slot,
  //  x1 = xln; x2T in x2's slot (channel-major LN2 output).
  float* xz   = ws;                    // 3145728
  float* xc   = xz  + 3145728;         // 1572864
  float* dbc  = xc  + 1572864;         // 573440
  float* dltT = dbc + 573440;          // 1572864
  float* yvT  = dltT + 1572864;        // 1572864 (TRANSPOSED y: [b][d][t])
  float* xln  = yvT + 1572864;         // 786432
  float* x2T  = xln + 786432;          // 786432 (channel-major: [Bi*192+ch][n])
  float* Xre  = x2T + 786432;          // 786432 (layout [(Bi*4+c)*48+d][k])
  float* Xim  = Xre + 786432;          // 786432
  float* duT = Xre;                    // 1572864 (spans Xre+Xim)
  float* x1 = xln;

  ln_kernel<<<1024, 256, 0, stream>>>(x, ln1_w, ln1_b, xln);
  gemm_tn<<<dim3(12, 64), 256, 0, stream>>>(xln, in_proj_w, nullptr, xz, 4096, 768, 192);
  conv_silu<<<1536, 256, 0, stream>>>(xz, conv_w, conv_b, xc);
  gemm_tn32<<<dim3(3, 128), 256, 0, stream>>>(xc, x_proj_w, nullptr, dbc, 4096, 140, 384);
  delta_trans<<<384, 256, 0, stream>>>(dbc, dt_proj_w, dt_proj_b, xc, dltT, duT);
  scan_fused<<<1536, 512, 0, stream>>>(dltT, duT, dbc, A_log, xc, xz, Dvec, yvT);
  gemm_at32<<<dim3(3, 128), 256, 0, stream>>>(yvT, out_proj_w, x, x1, 4096, 192, 384);
  ln2t_kernel<<<128, 256, 0, stream>>>(x1, ln2_w, ln2_b, x2T);
  fft_fwd<<<768, 256, 0, stream>>>(x2T, Xre, Xim);
  mix_fused<<<1024, 256, 0, stream>>>(Xre, Xim, cw1, cw2, cb1, cb2);
  fft_inv<<<768, 256, 0, stream>>>(Xre, Xim, x1, out);
}